// Round 2
// baseline (1188.726 us; speedup 1.0000x reference)
//
#include <hip/hip_runtime.h>
#include <math.h>

typedef unsigned short u16;
typedef unsigned int u32;

static inline int idiv(int a, int b) { return (a + b - 1) / b; }

__device__ inline float b2f_lo(u32 w) { return __uint_as_float((w & 0xFFFFu) << 16); }
__device__ inline float b2f_hi(u32 w) { return __uint_as_float(w & 0xFFFF0000u); }
__device__ inline u32 f2b_rne(float f) {            // round-to-nearest-even bf16 bits
    u32 x = __float_as_uint(f);
    return (x + 0x7FFFu + ((x >> 16) & 1u)) >> 16;
}

// ---------------- CSR build ----------------

__global__ void hist_kernel(const int* __restrict__ dst, int E, int n, int* __restrict__ cnt) {
    int e = blockIdx.x * 256 + threadIdx.x;
    if (e < E) {
        int d = dst[e];
        if ((unsigned)d < (unsigned)n) atomicAdd(&cnt[d], 1);
    }
}

__global__ void scan1_kernel(const int* __restrict__ cnt, int n,
                             int* __restrict__ rp, int* __restrict__ bsum) {
    __shared__ int s[256];
    int i = blockIdx.x * 256 + threadIdx.x;
    int v = (i < n) ? cnt[i] : 0;
    s[threadIdx.x] = v;
    __syncthreads();
    for (int off = 1; off < 256; off <<= 1) {
        int t = (threadIdx.x >= off) ? s[threadIdx.x - off] : 0;
        __syncthreads();
        s[threadIdx.x] += t;
        __syncthreads();
    }
    if (i < n) rp[i] = s[threadIdx.x] - v;
    if (threadIdx.x == 255) bsum[blockIdx.x] = s[255];
}

__global__ void scan2_kernel(int* __restrict__ bsum, int nb) {
    __shared__ int s[512];
    int v = ((int)threadIdx.x < nb) ? bsum[threadIdx.x] : 0;
    s[threadIdx.x] = v;
    __syncthreads();
    for (int off = 1; off < 512; off <<= 1) {
        int t = (threadIdx.x >= off) ? s[threadIdx.x - off] : 0;
        __syncthreads();
        s[threadIdx.x] += t;
        __syncthreads();
    }
    if ((int)threadIdx.x < nb) bsum[threadIdx.x] = s[threadIdx.x] - v;
}

__global__ void scan3_kernel(int* __restrict__ rp, int* __restrict__ cur,
                             float* __restrict__ dinv, const int* __restrict__ bsum,
                             int n, int E) {
    int i = blockIdx.x * 256 + threadIdx.x;
    if (i < n) {
        int c = cur[i];                    // still the count
        int v = rp[i] + bsum[blockIdx.x];
        rp[i]  = v;
        cur[i] = v;
        dinv[i] = 1.0f / (float)(c > 1 ? c : 1);
    }
    if (i == 0) rp[n] = E;
}

__global__ void fill_kernel(const int* __restrict__ src, const int* __restrict__ dst,
                            int E, int n, int* __restrict__ cur, int* __restrict__ col) {
    int e = blockIdx.x * 256 + threadIdx.x;
    if (e < E) {
        int d = dst[e];
        if ((unsigned)d < (unsigned)n) {
            int p = atomicAdd(&cur[d], 1);
            int s = src[e];
            if ((unsigned)s >= (unsigned)n) s = 0;
            col[p] = s;
        }
    }
}

// ---------------- mean aggregation (one wave per node) ----------------
// fp32 input, D = 128 (layer 1): lane holds 2 consecutive floats.
__global__ void agg_f32(const float* __restrict__ X, const int* __restrict__ rp,
                        const int* __restrict__ col, const float* __restrict__ dinv,
                        float* __restrict__ AGG, int r0, int rows) {
    const int lw   = (blockIdx.x * blockDim.x + threadIdx.x) >> 6;
    const int lane = threadIdx.x & 63;
    if (lw >= rows) return;
    const int node = r0 + lw;
    const int s = rp[node], e = rp[node + 1];
    float a0 = 0.f, a1 = 0.f;
    for (int t = s; t < e; ++t) {
        int c = col[t];
        const float2 v = *(const float2*)(X + (size_t)c * 128 + lane * 2);
        a0 += v.x; a1 += v.y;
    }
    const float inv = dinv[node];
    *(float2*)(AGG + (size_t)lw * 128 + lane * 2) = make_float2(a0 * inv, a1 * inv);
}

// bf16 input, D = NL*4: lanes [0, NL) each hold 4 consecutive elements.
template <int NL>
__global__ void agg_b16(const u16* __restrict__ X, const int* __restrict__ rp,
                        const int* __restrict__ col, const float* __restrict__ dinv,
                        float* __restrict__ AGG, int r0, int rows) {
    const int lw   = (blockIdx.x * blockDim.x + threadIdx.x) >> 6;
    const int lane = threadIdx.x & 63;
    if (lw >= rows) return;
    const int node = r0 + lw;
    const int D = NL * 4;
    if (lane >= NL) return;
    const int s = rp[node], e = rp[node + 1];
    float a0 = 0.f, a1 = 0.f, a2 = 0.f, a3 = 0.f;
    for (int t = s; t < e; ++t) {
        int c = col[t];
        const uint2 v = *(const uint2*)(X + (size_t)c * D + lane * 4);
        a0 += b2f_lo(v.x); a1 += b2f_hi(v.x);
        a2 += b2f_lo(v.y); a3 += b2f_hi(v.y);
    }
    const float inv = dinv[node];
    *(float4*)(AGG + (size_t)lw * D + lane * 4) =
        make_float4(a0 * inv, a1 * inv, a2 * inv, a3 * inv);
}

// ---------------- typed 4-element load/store helpers ----------------

template <typename T> struct Ld4;
template <> struct Ld4<float> {
    static __device__ inline void load(const float* p, float o[4]) {
        float4 v = *(const float4*)p;
        o[0] = v.x; o[1] = v.y; o[2] = v.z; o[3] = v.w;
    }
};
template <> struct Ld4<u16> {
    static __device__ inline void load(const u16* p, float o[4]) {
        uint2 v = *(const uint2*)p;
        o[0] = b2f_lo(v.x); o[1] = b2f_hi(v.x);
        o[2] = b2f_lo(v.y); o[3] = b2f_hi(v.y);
    }
};

template <typename T> struct St4;
template <> struct St4<float> {
    static __device__ inline void store(float* p, const float v[4]) {
        *(float4*)p = make_float4(v[0], v[1], v[2], v[3]);
    }
};
template <> struct St4<u16> {
    static __device__ inline void store(u16* p, const float v[4]) {
        u32 a = f2b_rne(v[0]) | (f2b_rne(v[1]) << 16);
        u32 b = f2b_rne(v[2]) | (f2b_rne(v[3]) << 16);
        *(uint2*)p = make_uint2(a, b);
    }
};

// ---------------- fused dual GEMM: H = act(A1@W1 + A2@W2 + b) ----------------
// A1: fp32 chunk-local rows [0, rowsC); A2: global rows; output global rows.
// BM=64, BK=32, thread computes 4x4.  ACT: 0=tanh 1=relu 2=sigmoid
template <typename TA2, typename TOUT, int DIN, int DOUT, int BN, int ACT>
__global__ __launch_bounds__(16 * (BN / 4))
void gemm_kernel(const float* __restrict__ A1, const TA2* __restrict__ A2,
                 const float* __restrict__ W1, const float* __restrict__ W2,
                 const float* __restrict__ bias, TOUT* __restrict__ Hout,
                 int n, int r0, int rowsC) {
    constexpr int BM = 64, BK = 32;
    constexpr int NT = 16 * (BN / 4);
    __shared__ float As[BK][BM + 4];
    __shared__ float Ws[BK][BN + 4];

    const int row0l = blockIdx.x * BM;      // chunk-local
    const int row0g = r0 + row0l;           // global
    const int bn0   = blockIdx.y * BN;
    const int t  = threadIdx.x;
    const int ct = t % (BN / 4);
    const int rt = t / (BN / 4);

    float acc[4][4];
#pragma unroll
    for (int i = 0; i < 4; ++i)
#pragma unroll
        for (int j = 0; j < 4; ++j) acc[i][j] = 0.f;

#pragma unroll
    for (int pass = 0; pass < 2; ++pass) {
        const float* W = pass ? W2 : W1;
        for (int kt = 0; kt < DIN / BK; ++kt) {
            // stage A tile (BM x BK), 4 elems per thread-iteration, transpose into LDS
#pragma unroll
            for (int l = 0; l < BM * (BK / 4); l += NT) {
                int li = l + t;
                int kv = li & (BK / 4 - 1);
                int r  = li >> 3;
                float v[4];
                if (pass == 0) {
                    int rr = row0l + r; if (rr >= rowsC) rr = rowsC - 1;
                    Ld4<float>::load(A1 + (size_t)rr * DIN + kt * BK + kv * 4, v);
                } else {
                    int rr = row0g + r; if (rr >= n) rr = n - 1;
                    Ld4<TA2>::load(A2 + (size_t)rr * DIN + kt * BK + kv * 4, v);
                }
                As[kv * 4 + 0][r] = v[0];
                As[kv * 4 + 1][r] = v[1];
                As[kv * 4 + 2][r] = v[2];
                As[kv * 4 + 3][r] = v[3];
            }
            // stage W tile (BK x BN)
#pragma unroll
            for (int l = 0; l < BK * (BN / 4); l += NT) {
                int li = l + t;
                int cv = li % (BN / 4);
                int k  = li / (BN / 4);
                *(float4*)&Ws[k][cv * 4] =
                    *(const float4*)(W + (size_t)(kt * BK + k) * DOUT + bn0 + cv * 4);
            }
            __syncthreads();
#pragma unroll
            for (int k = 0; k < BK; ++k) {
                float4 a = *(const float4*)&As[k][rt * 4];
                float4 w = *(const float4*)&Ws[k][ct * 4];
                float av[4] = {a.x, a.y, a.z, a.w};
                float wv[4] = {w.x, w.y, w.z, w.w};
#pragma unroll
                for (int i = 0; i < 4; ++i)
#pragma unroll
                    for (int j = 0; j < 4; ++j) acc[i][j] += av[i] * wv[j];
            }
            __syncthreads();
        }
    }

    // epilogue
    float4 bv = *(const float4*)(bias + bn0 + ct * 4);
    float bb[4] = {bv.x, bv.y, bv.z, bv.w};
    const int rowEnd = r0 + rowsC;
#pragma unroll
    for (int i = 0; i < 4; ++i) {
        int row = row0g + rt * 4 + i;
        if (row < rowEnd) {
            float ov[4];
#pragma unroll
            for (int j = 0; j < 4; ++j) {
                float v = acc[i][j] + bb[j];
                if (ACT == 0)      v = tanhf(v);
                else if (ACT == 1) v = fmaxf(v, 0.f);
                else               v = 1.0f / (1.0f + __expf(-v));
                ov[j] = v;
            }
            St4<TOUT>::store(Hout + (size_t)row * DOUT + bn0 + ct * 4, ov);
        }
    }
}

// ---------------- launch ----------------

extern "C" void kernel_launch(void* const* d_in, const int* in_sizes, int n_in,
                              void* d_out, int out_size, void* d_ws, size_t ws_size,
                              hipStream_t stream) {
    const float* x   = (const float*)d_in[0];
    const int*   ei  = (const int*)  d_in[1];
    const float* W1l = (const float*)d_in[2];
    const float* W1r = (const float*)d_in[3];
    const float* b1  = (const float*)d_in[4];
    const float* W2l = (const float*)d_in[5];
    const float* W2r = (const float*)d_in[6];
    const float* b2  = (const float*)d_in[7];
    const float* W3l = (const float*)d_in[8];
    const float* W3r = (const float*)d_in[9];
    const float* b3  = (const float*)d_in[10];
    float* out = (float*)d_out;

    const int n = in_sizes[0] / 128;   // 100000
    const int E = in_sizes[1] / 2;     // 1600000
    const int* esrc = ei;
    const int* edst = ei + E;

    char* ws = (char*)d_ws;
    size_t off = 0;
    auto alloc = [&](size_t bytes) -> void* {
        void* p = ws + off;
        off += (bytes + 255) & ~(size_t)255;
        return p;
    };
    int*   rp   = (int*)  alloc((size_t)(n + 1) * 4);
    int*   cur  = (int*)  alloc((size_t)n * 4);
    int*   colx = (int*)  alloc((size_t)E * 4);
    float* dinv = (float*)alloc((size_t)n * 4);
    int*   bsum = (int*)  alloc(512 * 4);
    u16*   H1b  = (u16*)  alloc((size_t)n * 256 * 2);   // bf16
    u16*   H2b  = (u16*)  alloc((size_t)n * 192 * 2);   // bf16
    const size_t fixed = off;

    if (ws_size < fixed + (size_t)64 * 256 * 4) return;  // can't fit: fail cleanly, no fault

    // AGG chunk (fp32, 256 floats/row capacity) takes the remaining workspace
    size_t rem = ws_size - fixed;
    int CH = (int)(rem / ((size_t)256 * 4));
    CH = (CH / 64) * 64;
    const int nUp = idiv(n, 64) * 64;
    if (CH > nUp) CH = nUp;
    float* AGGc = (float*)(ws + fixed);

    const int NB = idiv(n, 256);

    hipMemsetAsync(cur, 0, (size_t)n * 4, stream);
    hist_kernel <<<idiv(E, 256), 256, 0, stream>>>(edst, E, n, cur);
    scan1_kernel<<<NB, 256, 0, stream>>>(cur, n, rp, bsum);
    scan2_kernel<<<1, 512, 0, stream>>>(bsum, NB);
    scan3_kernel<<<NB, 256, 0, stream>>>(rp, cur, dinv, bsum, n, E);
    fill_kernel <<<idiv(E, 256), 256, 0, stream>>>(esrc, edst, E, n, cur, colx);

    // layer 1: 128 -> 256, tanh;  A2 = x (fp32), out H1b (bf16)
    for (int r0 = 0; r0 < n; r0 += CH) {
        int rows = n - r0 < CH ? n - r0 : CH;
        agg_f32<<<idiv(rows, 4), 256, 0, stream>>>(x, rp, colx, dinv, AGGc, r0, rows);
        gemm_kernel<float, u16, 128, 256, 64, 0>
            <<<dim3(idiv(rows, 64), 4), 256, 0, stream>>>(
                AGGc, x, W1l, W1r, b1, H1b, n, r0, rows);
    }

    // layer 2: 256 -> 192, relu;  A2 = H1b (bf16), out H2b (bf16)
    for (int r0 = 0; r0 < n; r0 += CH) {
        int rows = n - r0 < CH ? n - r0 : CH;
        agg_b16<64><<<idiv(rows, 4), 256, 0, stream>>>(H1b, rp, colx, dinv, AGGc, r0, rows);
        gemm_kernel<u16, u16, 256, 192, 64, 1>
            <<<dim3(idiv(rows, 64), 3), 256, 0, stream>>>(
                AGGc, H1b, W2l, W2r, b2, H2b, n, r0, rows);
    }

    // layer 3: 192 -> 32, sigmoid;  A2 = H2b (bf16), out = d_out (fp32)
    for (int r0 = 0; r0 < n; r0 += CH) {
        int rows = n - r0 < CH ? n - r0 : CH;
        agg_b16<48><<<idiv(rows, 4), 256, 0, stream>>>(H2b, rp, colx, dinv, AGGc, r0, rows);
        gemm_kernel<u16, float, 192, 32, 32, 2>
            <<<dim3(idiv(rows, 64), 1), 128, 0, stream>>>(
                AGGc, H2b, W3l, W3r, b3, out, n, r0, rows);
    }
}

// Round 3
// 756.484 us; speedup vs baseline: 1.5714x; 1.5714x over previous
//
#include <hip/hip_runtime.h>
#include <math.h>

typedef unsigned short u16;
typedef unsigned int u32;
typedef __attribute__((ext_vector_type(8))) short bf16x8;
typedef __attribute__((ext_vector_type(4))) float f32x4;

static inline int idiv(int a, int b) { return (a + b - 1) / b; }

__device__ inline float b2f_lo(u32 w) { return __uint_as_float((w & 0xFFFFu) << 16); }
__device__ inline float b2f_hi(u32 w) { return __uint_as_float(w & 0xFFFF0000u); }
__device__ inline u32 f2b_rne(float f) {            // round-to-nearest-even bf16 bits
    u32 x = __float_as_uint(f);
    return (x + 0x7FFFu + ((x >> 16) & 1u)) >> 16;
}

// ---------------- CSR build (unchanged from round 2, verified) ----------------

__global__ void hist_kernel(const int* __restrict__ dst, int E, int n, int* __restrict__ cnt) {
    int e = blockIdx.x * 256 + threadIdx.x;
    if (e < E) {
        int d = dst[e];
        if ((unsigned)d < (unsigned)n) atomicAdd(&cnt[d], 1);
    }
}

__global__ void scan1_kernel(const int* __restrict__ cnt, int n,
                             int* __restrict__ rp, int* __restrict__ bsum) {
    __shared__ int s[256];
    int i = blockIdx.x * 256 + threadIdx.x;
    int v = (i < n) ? cnt[i] : 0;
    s[threadIdx.x] = v;
    __syncthreads();
    for (int off = 1; off < 256; off <<= 1) {
        int t = (threadIdx.x >= off) ? s[threadIdx.x - off] : 0;
        __syncthreads();
        s[threadIdx.x] += t;
        __syncthreads();
    }
    if (i < n) rp[i] = s[threadIdx.x] - v;
    if (threadIdx.x == 255) bsum[blockIdx.x] = s[255];
}

__global__ void scan2_kernel(int* __restrict__ bsum, int nb) {
    __shared__ int s[512];
    int v = ((int)threadIdx.x < nb) ? bsum[threadIdx.x] : 0;
    s[threadIdx.x] = v;
    __syncthreads();
    for (int off = 1; off < 512; off <<= 1) {
        int t = (threadIdx.x >= off) ? s[threadIdx.x - off] : 0;
        __syncthreads();
        s[threadIdx.x] += t;
        __syncthreads();
    }
    if ((int)threadIdx.x < nb) bsum[threadIdx.x] = s[threadIdx.x] - v;
}

__global__ void scan3_kernel(int* __restrict__ rp, int* __restrict__ cur,
                             float* __restrict__ dinv, const int* __restrict__ bsum,
                             int n, int E) {
    int i = blockIdx.x * 256 + threadIdx.x;
    if (i < n) {
        int c = cur[i];                    // still the count
        int v = rp[i] + bsum[blockIdx.x];
        rp[i]  = v;
        cur[i] = v;
        dinv[i] = 1.0f / (float)(c > 1 ? c : 1);
    }
    if (i == 0) rp[n] = E;
}

__global__ void fill_kernel(const int* __restrict__ src, const int* __restrict__ dst,
                            int E, int n, int* __restrict__ cur, int* __restrict__ col) {
    int e = blockIdx.x * 256 + threadIdx.x;
    if (e < E) {
        int d = dst[e];
        if ((unsigned)d < (unsigned)n) {
            int p = atomicAdd(&cur[d], 1);
            int s = src[e];
            if ((unsigned)s >= (unsigned)n) s = 0;
            col[p] = s;
        }
    }
}

// ---------------- prep kernels ----------------

// dst[N][K] (bf16) = transpose of src[K][N] (fp32)
__global__ void tr_cvt(const float* __restrict__ src, u16* __restrict__ dst, int K, int N) {
    int i = blockIdx.x * 256 + threadIdx.x;
    if (i >= K * N) return;
    int nn = i / K, k = i - nn * K;
    dst[i] = (u16)f2b_rne(src[(size_t)k * N + nn]);
}

// dst[0:D] = 0, dst[D:2D] = b
__global__ void bias_cat(const float* __restrict__ b, float* __restrict__ dst, int D) {
    int i = blockIdx.x * 256 + threadIdx.x;
    if (i < 2 * D) dst[i] = (i < D) ? 0.f : b[i - D];
}

// xb = bf16(x), 8 elems/thread
__global__ void cvt_x_kernel(const float* __restrict__ x, u16* __restrict__ xb, int total8) {
    int i = blockIdx.x * 256 + threadIdx.x;
    if (i >= total8) return;
    const float4 a = *(const float4*)(x + (size_t)i * 8);
    const float4 b = *(const float4*)(x + (size_t)i * 8 + 4);
    uint4 o;
    o.x = f2b_rne(a.x) | (f2b_rne(a.y) << 16);
    o.y = f2b_rne(a.z) | (f2b_rne(a.w) << 16);
    o.z = f2b_rne(b.x) | (f2b_rne(b.y) << 16);
    o.w = f2b_rne(b.z) | (f2b_rne(b.w) << 16);
    *(uint4*)(xb + (size_t)i * 8) = o;
}

// ---------------- aggregation kernels ----------------

// AGG1[i] = mean_j xb[col[j]]  (128-d bf16 -> bf16); one wave per node, 2 elems/lane
__global__ void agg_mean128(const u16* __restrict__ X, const int* __restrict__ rp,
                            const int* __restrict__ col, const float* __restrict__ dinv,
                            u16* __restrict__ A, int n) {
    const int lw   = (blockIdx.x * blockDim.x + threadIdx.x) >> 6;
    const int lane = threadIdx.x & 63;
    if (lw >= n) return;
    const int s = rp[lw], e = rp[lw + 1];
    float a0 = 0.f, a1 = 0.f;
    for (int t = s; t < e; ++t) {
        int c = col[t];
        u32 v = *(const u32*)(X + (size_t)c * 128 + lane * 2);
        a0 += b2f_lo(v); a1 += b2f_hi(v);
    }
    const float inv = dinv[lw];
    *(u32*)(A + (size_t)lw * 128 + lane * 2) =
        f2b_rne(a0 * inv) | (f2b_rne(a1 * inv) << 16);
}

// H2[i] = relu(mean_j Y[col[j]][0:192] + Y[i][192:384]); one wave/node, lanes 0-47 x 4 elems
__global__ void agg_cat192(const u16* __restrict__ Y, const int* __restrict__ rp,
                           const int* __restrict__ col, const float* __restrict__ dinv,
                           u16* __restrict__ H, int n) {
    const int lw   = (blockIdx.x * blockDim.x + threadIdx.x) >> 6;
    const int lane = threadIdx.x & 63;
    if (lw >= n || lane >= 48) return;
    const int s = rp[lw], e = rp[lw + 1];
    float a0 = 0.f, a1 = 0.f, a2 = 0.f, a3 = 0.f;
    for (int t = s; t < e; ++t) {
        int c = col[t];
        uint2 v = *(const uint2*)(Y + (size_t)c * 384 + lane * 4);
        a0 += b2f_lo(v.x); a1 += b2f_hi(v.x);
        a2 += b2f_lo(v.y); a3 += b2f_hi(v.y);
    }
    const float inv = dinv[lw];
    uint2 rv = *(const uint2*)(Y + (size_t)lw * 384 + 192 + lane * 4);
    float o0 = fmaxf(a0 * inv + b2f_lo(rv.x), 0.f);
    float o1 = fmaxf(a1 * inv + b2f_hi(rv.x), 0.f);
    float o2 = fmaxf(a2 * inv + b2f_lo(rv.y), 0.f);
    float o3 = fmaxf(a3 * inv + b2f_hi(rv.y), 0.f);
    uint2 o;
    o.x = f2b_rne(o0) | (f2b_rne(o1) << 16);
    o.y = f2b_rne(o2) | (f2b_rne(o3) << 16);
    *(uint2*)(H + (size_t)lw * 192 + lane * 4) = o;
}

// out[i] = sigmoid(mean_j Y[col[j]][0:32] + Y[i][32:64]); 4 nodes/wave, 16 lanes x 2 elems
__global__ void agg_cat32(const u16* __restrict__ Y, const int* __restrict__ rp,
                          const int* __restrict__ col, const float* __restrict__ dinv,
                          float* __restrict__ out, int n) {
    const int widx = (blockIdx.x * blockDim.x + threadIdx.x) >> 6;
    const int lane = threadIdx.x & 63;
    const int node = widx * 4 + (lane >> 4);
    const int sl   = lane & 15;
    if (node >= n) return;
    const int s = rp[node], e = rp[node + 1];
    float a0 = 0.f, a1 = 0.f;
    for (int t = s; t < e; ++t) {
        int c = col[t];
        u32 v = *(const u32*)(Y + (size_t)c * 64 + sl * 2);
        a0 += b2f_lo(v); a1 += b2f_hi(v);
    }
    const float inv = dinv[node];
    u32 rv = *(const u32*)(Y + (size_t)node * 64 + 32 + sl * 2);
    float o0 = 1.f / (1.f + __expf(-(a0 * inv + b2f_lo(rv))));
    float o1 = 1.f / (1.f + __expf(-(a1 * inv + b2f_hi(rv))));
    *(float2*)(out + (size_t)node * 32 + sl * 2) = make_float2(o0, o1);
}

// ---------------- MFMA GEMM: out = act(A1@B1t^T [+ A2@B2t^T] + bias) ----------------
// A: [M][KDIM] bf16 row-major; Bt: [NDIM][KDIM] bf16 (pre-transposed weights).
// BM=128; BN=128 -> 2x2 waves (64x64/wave); BN=64 -> 4x1 waves (32x64/wave).
// LDS tiles [rows][64] bf16 with 8-elem-chunk XOR swizzle (chunk ^= row&7), no padding.
// ACT: 0 = tanh, -1 = none.
template <int KDIM, int NDIM, int BN, int ACT, bool DUAL>
__global__ __launch_bounds__(256)
void gemm_mfma(const u16* __restrict__ A1, const u16* __restrict__ A2,
               const u16* __restrict__ B1t, const u16* __restrict__ B2t,
               const float* __restrict__ bias, u16* __restrict__ out, int M) {
    constexpr int BM = 128;
    constexpr int WR = (BN == 128) ? 2 : 4;
    constexpr int MF = BM / WR / 16;    // 4 (BN=128) or 2 (BN=64)
    constexpr int NF = 4;               // 64/16
    __shared__ u16 As[BM * 64];
    __shared__ u16 Bs[BN * 64];

    const int row0 = blockIdx.x * BM;
    const int bn0  = blockIdx.y * BN;
    const int t    = threadIdx.x;
    const int wid  = t >> 6, ln = t & 63;
    const int ln15 = ln & 15, lg = ln >> 4;
    const int wr = (BN == 128) ? (wid >> 1) : wid;
    const int wc = (BN == 128) ? (wid & 1) : 0;
    const int wrow0 = wr * (BM / WR);
    const int wcol0 = wc * 64;

    f32x4 acc[MF][NF];
#pragma unroll
    for (int m = 0; m < MF; ++m)
#pragma unroll
        for (int nn = 0; nn < NF; ++nn) acc[m][nn] = (f32x4){0.f, 0.f, 0.f, 0.f};

#pragma unroll
    for (int s = 0; s < (DUAL ? 2 : 1); ++s) {
        const u16* A  = (DUAL && s) ? A2 : A1;
        const u16* Bt = (DUAL && s) ? B2t : B1t;
        for (int kt = 0; kt < KDIM / 64; ++kt) {
            const int k0 = kt * 64;
            // stage A tile (128 x 64), 16B per thread-iter, XOR-swizzled chunks
#pragma unroll
            for (int it = 0; it < 4; ++it) {
                int r = (t >> 3) + it * 32;
                int c = t & 7;
                int row = row0 + r; if (row >= M) row = M - 1;
                uint4 v = *(const uint4*)(A + (size_t)row * KDIM + k0 + c * 8);
                *(uint4*)(As + r * 64 + ((c ^ (r & 7)) * 8)) = v;
            }
            // stage B tile (BN x 64)
#pragma unroll
            for (int it = 0; it < BN / 32; ++it) {
                int r = (t >> 3) + it * 32;
                int c = t & 7;
                uint4 v = *(const uint4*)(Bt + (size_t)(bn0 + r) * KDIM + k0 + c * 8);
                *(uint4*)(Bs + r * 64 + ((c ^ (r & 7)) * 8)) = v;
            }
            __syncthreads();
#pragma unroll
            for (int ks = 0; ks < 2; ++ks) {
                bf16x8 af[MF], bfr[NF];
#pragma unroll
                for (int m = 0; m < MF; ++m) {
                    int r  = wrow0 + m * 16 + ln15;
                    int ch = (ks * 4 + lg) ^ (r & 7);
                    af[m] = *(const bf16x8*)(As + r * 64 + ch * 8);
                }
#pragma unroll
                for (int nn = 0; nn < NF; ++nn) {
                    int r  = wcol0 + nn * 16 + ln15;
                    int ch = (ks * 4 + lg) ^ (r & 7);
                    bfr[nn] = *(const bf16x8*)(Bs + r * 64 + ch * 8);
                }
#pragma unroll
                for (int m = 0; m < MF; ++m)
#pragma unroll
                    for (int nn = 0; nn < NF; ++nn)
                        acc[m][nn] = __builtin_amdgcn_mfma_f32_16x16x32_bf16(
                            af[m], bfr[nn], acc[m][nn], 0, 0, 0);
            }
            __syncthreads();
        }
    }

    // epilogue: C/D layout col = lane&15, row = (lane>>4)*4 + reg
#pragma unroll
    for (int nn = 0; nn < NF; ++nn) {
        const int col = bn0 + wcol0 + nn * 16 + ln15;
        const float bv = bias[col];
#pragma unroll
        for (int m = 0; m < MF; ++m) {
#pragma unroll
            for (int r = 0; r < 4; ++r) {
                int row = row0 + wrow0 + m * 16 + lg * 4 + r;
                if (row < M) {
                    float v = acc[m][nn][r] + bv;
                    if (ACT == 0) v = tanhf(v);
                    out[(size_t)row * NDIM + col] = (u16)f2b_rne(v);
                }
            }
        }
    }
}

// ---------------- launch ----------------

extern "C" void kernel_launch(void* const* d_in, const int* in_sizes, int n_in,
                              void* d_out, int out_size, void* d_ws, size_t ws_size,
                              hipStream_t stream) {
    const float* x   = (const float*)d_in[0];
    const int*   ei  = (const int*)  d_in[1];
    const float* W1l = (const float*)d_in[2];
    const float* W1r = (const float*)d_in[3];
    const float* b1  = (const float*)d_in[4];
    const float* W2l = (const float*)d_in[5];
    const float* W2r = (const float*)d_in[6];
    const float* b2  = (const float*)d_in[7];
    const float* W3l = (const float*)d_in[8];
    const float* W3r = (const float*)d_in[9];
    const float* b3  = (const float*)d_in[10];
    float* out = (float*)d_out;

    const int n = in_sizes[0] / 128;   // 100000
    const int E = in_sizes[1] / 2;     // 1600000
    const int* esrc = ei;
    const int* edst = ei + E;

    char* ws = (char*)d_ws;
    size_t off = 0;
    auto alloc = [&](size_t bytes) -> void* {
        void* p = ws + off;
        off += (bytes + 255) & ~(size_t)255;
        return p;
    };
    int*   rp    = (int*)  alloc((size_t)(n + 1) * 4);
    int*   cur   = (int*)  alloc((size_t)n * 4);
    int*   colx  = (int*)  alloc((size_t)E * 4);
    float* dinv  = (float*)alloc((size_t)n * 4);
    int*   bsum  = (int*)  alloc(512 * 4);
    u16*   W1lt  = (u16*)  alloc(256 * 128 * 2);
    u16*   W1rt  = (u16*)  alloc(256 * 128 * 2);
    u16*   W2t   = (u16*)  alloc(384 * 256 * 2);
    u16*   W3t   = (u16*)  alloc(64 * 192 * 2);
    float* b2cat = (float*)alloc(384 * 4);
    float* b3cat = (float*)alloc(64 * 4);
    u16*   Sa    = (u16*)  alloc((size_t)n * 384 * 2);  // xb+AGG1 -> Y2cat -> Y3cat
    u16*   Sb    = (u16*)  alloc((size_t)n * 256 * 2);  // H1 -> H2

    if (off > ws_size) return;   // insufficient workspace: fail cleanly (no fault)

    u16* xb   = Sa;
    u16* AGG1 = Sa + (size_t)n * 128;
    u16* Y2   = Sa;              // after xb/AGG1 are dead
    u16* Y3   = Sa;              // after Y2 is dead
    u16* H1   = Sb;
    u16* H2   = Sb;              // after H1 is dead

    const int NB = idiv(n, 256);
    const int GX = idiv(n, 128); // 782

    // CSR
    hipMemsetAsync(cur, 0, (size_t)n * 4, stream);
    hist_kernel <<<idiv(E, 256), 256, 0, stream>>>(edst, E, n, cur);
    scan1_kernel<<<NB, 256, 0, stream>>>(cur, n, rp, bsum);
    scan2_kernel<<<1, 512, 0, stream>>>(bsum, NB);
    scan3_kernel<<<NB, 256, 0, stream>>>(rp, cur, dinv, bsum, n, E);
    fill_kernel <<<idiv(E, 256), 256, 0, stream>>>(esrc, edst, E, n, cur, colx);

    // weight prep (bf16, transposed, concatenated) + bias cats + xb
    tr_cvt<<<idiv(128 * 256, 256), 256, 0, stream>>>(W1l, W1lt, 128, 256);
    tr_cvt<<<idiv(128 * 256, 256), 256, 0, stream>>>(W1r, W1rt, 128, 256);
    tr_cvt<<<idiv(256 * 192, 256), 256, 0, stream>>>(W2l, W2t, 256, 192);
    tr_cvt<<<idiv(256 * 192, 256), 256, 0, stream>>>(W2r, W2t + 192 * 256, 256, 192);
    tr_cvt<<<idiv(192 * 32, 256), 256, 0, stream>>>(W3l, W3t, 192, 32);
    tr_cvt<<<idiv(192 * 32, 256), 256, 0, stream>>>(W3r, W3t + 32 * 192, 192, 32);
    bias_cat<<<2, 256, 0, stream>>>(b2, b2cat, 192);
    bias_cat<<<1, 256, 0, stream>>>(b3, b3cat, 32);
    cvt_x_kernel<<<idiv(n * 16, 256), 256, 0, stream>>>(x, xb, n * 16);

    // layer 1 (aggregate-first): H1 = tanh(AGG1@W1l + xb@W1r + b1)
    agg_mean128<<<idiv(n, 4), 256, 0, stream>>>(xb, rp, colx, dinv, AGG1, n);
    gemm_mfma<128, 256, 128, 0, true><<<dim3(GX, 2), 256, 0, stream>>>(
        AGG1, xb, W1lt, W1rt, b1, H1, n);

    // layer 2 (transform-first): Y2 = H1@[W2l|W2r] + [0|b2]; H2 = relu(agg(Y2l)+Y2r)
    gemm_mfma<256, 384, 128, -1, false><<<dim3(GX, 3), 256, 0, stream>>>(
        H1, (const u16*)nullptr, W2t, (const u16*)nullptr, b2cat, Y2, n);
    agg_cat192<<<idiv(n, 4), 256, 0, stream>>>(Y2, rp, colx, dinv, H2, n);

    // layer 3 (transform-first): Y3 = H2@[W3l|W3r] + [0|b3]; out = sigmoid(agg(Y3l)+Y3r)
    gemm_mfma<192, 64, 64, -1, false><<<dim3(GX, 1), 256, 0, stream>>>(
        H2, (const u16*)nullptr, W3t, (const u16*)nullptr, b3cat, Y3, n);
    agg_cat32<<<idiv(n, 16), 256, 0, stream>>>(Y3, rp, colx, dinv, out, n);
}

// Round 4
// 563.650 us; speedup vs baseline: 2.1090x; 1.3421x over previous
//
#include <hip/hip_runtime.h>
#include <math.h>

typedef unsigned short u16;
typedef unsigned int u32;
typedef __attribute__((ext_vector_type(8))) short bf16x8;
typedef __attribute__((ext_vector_type(4))) float f32x4;

static inline int idiv(int a, int b) { return (a + b - 1) / b; }

__device__ inline float b2f_lo(u32 w) { return __uint_as_float((w & 0xFFFFu) << 16); }
__device__ inline float b2f_hi(u32 w) { return __uint_as_float(w & 0xFFFF0000u); }
__device__ inline u32 f2b_rne(float f) {            // round-to-nearest-even bf16 bits
    u32 x = __float_as_uint(f);
    return (x + 0x7FFFu + ((x >> 16) & 1u)) >> 16;
}

// ---------------- CSR build (verified rounds 2-3) ----------------

__global__ void hist_kernel(const int* __restrict__ dst, int E, int n, int* __restrict__ cnt) {
    int e = blockIdx.x * 256 + threadIdx.x;
    if (e < E) {
        int d = dst[e];
        if ((unsigned)d < (unsigned)n) atomicAdd(&cnt[d], 1);
    }
}

__global__ void scan1_kernel(const int* __restrict__ cnt, int n,
                             int* __restrict__ rp, int* __restrict__ bsum) {
    __shared__ int s[256];
    int i = blockIdx.x * 256 + threadIdx.x;
    int v = (i < n) ? cnt[i] : 0;
    s[threadIdx.x] = v;
    __syncthreads();
    for (int off = 1; off < 256; off <<= 1) {
        int t = (threadIdx.x >= off) ? s[threadIdx.x - off] : 0;
        __syncthreads();
        s[threadIdx.x] += t;
        __syncthreads();
    }
    if (i < n) rp[i] = s[threadIdx.x] - v;
    if (threadIdx.x == 255) bsum[blockIdx.x] = s[255];
}

__global__ void scan2_kernel(int* __restrict__ bsum, int nb) {
    __shared__ int s[512];
    int v = ((int)threadIdx.x < nb) ? bsum[threadIdx.x] : 0;
    s[threadIdx.x] = v;
    __syncthreads();
    for (int off = 1; off < 512; off <<= 1) {
        int t = (threadIdx.x >= off) ? s[threadIdx.x - off] : 0;
        __syncthreads();
        s[threadIdx.x] += t;
        __syncthreads();
    }
    if ((int)threadIdx.x < nb) bsum[threadIdx.x] = s[threadIdx.x] - v;
}

__global__ void scan3_kernel(int* __restrict__ rp, int* __restrict__ cur,
                             float* __restrict__ dinv, const int* __restrict__ bsum,
                             int n, int E) {
    int i = blockIdx.x * 256 + threadIdx.x;
    if (i < n) {
        int c = cur[i];                    // still the count
        int v = rp[i] + bsum[blockIdx.x];
        rp[i]  = v;
        cur[i] = v;
        dinv[i] = 1.0f / (float)(c > 1 ? c : 1);
    }
    if (i == 0) rp[n] = E;
}

__global__ void fill_kernel(const int* __restrict__ src, const int* __restrict__ dst,
                            int E, int n, int* __restrict__ cur, int* __restrict__ col) {
    int e = blockIdx.x * 256 + threadIdx.x;
    if (e < E) {
        int d = dst[e];
        if ((unsigned)d < (unsigned)n) {
            int p = atomicAdd(&cur[d], 1);
            int s = src[e];
            if ((unsigned)s >= (unsigned)n) s = 0;
            col[p] = s;
        }
    }
}

// ---------------- fused prep: all weight transposes + bias cats in one launch ----------------
// seg sizes: 32768,32768,49152,49152,6144,6144,384,64  (total 176576)
__global__ void prep_all(const float* __restrict__ W1l, const float* __restrict__ W1r,
                         const float* __restrict__ W2l, const float* __restrict__ W2r,
                         const float* __restrict__ W3l, const float* __restrict__ W3r,
                         const float* __restrict__ b2, const float* __restrict__ b3,
                         u16* __restrict__ W1lt, u16* __restrict__ W1rt,
                         u16* __restrict__ W2t, u16* __restrict__ W3t,
                         float* __restrict__ b2cat, float* __restrict__ b3cat) {
    int i = blockIdx.x * 256 + threadIdx.x;
    if (i < 32768) {                       // W1l^T: K=128, N=256
        int nn = i >> 7, k = i & 127;
        W1lt[i] = (u16)f2b_rne(W1l[k * 256 + nn]);
        return;
    }
    i -= 32768;
    if (i < 32768) {
        int nn = i >> 7, k = i & 127;
        W1rt[i] = (u16)f2b_rne(W1r[k * 256 + nn]);
        return;
    }
    i -= 32768;
    if (i < 49152) {                       // W2l^T: K=256, N=192
        int nn = i >> 8, k = i & 255;
        W2t[i] = (u16)f2b_rne(W2l[k * 192 + nn]);
        return;
    }
    i -= 49152;
    if (i < 49152) {
        int nn = i >> 8, k = i & 255;
        W2t[192 * 256 + i] = (u16)f2b_rne(W2r[k * 192 + nn]);
        return;
    }
    i -= 49152;
    if (i < 6144) {                        // W3l^T: K=192, N=32
        int nn = i / 192, k = i - nn * 192;
        W3t[i] = (u16)f2b_rne(W3l[k * 32 + nn]);
        return;
    }
    i -= 6144;
    if (i < 6144) {
        int nn = i / 192, k = i - nn * 192;
        W3t[32 * 192 + i] = (u16)f2b_rne(W3r[k * 32 + nn]);
        return;
    }
    i -= 6144;
    if (i < 384) { b2cat[i] = (i < 192) ? 0.f : b2[i - 192]; return; }
    i -= 384;
    if (i < 64)  { b3cat[i] = (i < 32) ? 0.f : b3[i - 32]; }
}

// xb = bf16(x), 8 elems/thread
__global__ void cvt_x_kernel(const float* __restrict__ x, u16* __restrict__ xb, int total8) {
    int i = blockIdx.x * 256 + threadIdx.x;
    if (i >= total8) return;
    const float4 a = *(const float4*)(x + (size_t)i * 8);
    const float4 b = *(const float4*)(x + (size_t)i * 8 + 4);
    uint4 o;
    o.x = f2b_rne(a.x) | (f2b_rne(a.y) << 16);
    o.y = f2b_rne(a.z) | (f2b_rne(a.w) << 16);
    o.z = f2b_rne(b.x) | (f2b_rne(b.y) << 16);
    o.w = f2b_rne(b.z) | (f2b_rne(b.w) << 16);
    *(uint4*)(xb + (size_t)i * 8) = o;
}

// ---------------- aggregation kernels: MLP-optimized gathers ----------------
// Pattern: 2 nodes per wave (32 lanes each) or 4 nodes (16 lanes each);
// uniform loop to pair-max degree; branchless unrolled loads (clamped index,
// cndmask-zeroed masked slots) -> 4-6 loads in flight per lane.

// AGG1[i] = mean_j xb[col[j]]  (128 bf16). 2 nodes/wave, 32 lanes x uint2, unroll 4.
__global__ void agg_mean128(const u16* __restrict__ X, const int* __restrict__ rp,
                            const int* __restrict__ col, const float* __restrict__ dinv,
                            u16* __restrict__ A, int n, int E) {
    const int widx = (blockIdx.x * blockDim.x + threadIdx.x) >> 6;
    const int lane = threadIdx.x & 63;
    const int half = lane >> 5, sl = lane & 31;
    const int node = widx * 2 + half;
    const bool valid = node < n;
    const int s   = valid ? rp[node] : 0;
    const int deg = valid ? rp[node + 1] - s : 0;
    int m = deg;
    m = max(m, __shfl_xor(m, 32));
    const uint2* Xg = (const uint2*)X;     // row = 32 x uint2
    float a0 = 0, a1 = 0, a2 = 0, a3 = 0;
    float c0f = 0, c1f = 0, c2f = 0, c3f = 0;
    for (int t = 0; t < m; t += 4) {
        bool p0 = t < deg, p1 = t + 1 < deg, p2 = t + 2 < deg, p3 = t + 3 < deg;
        int i0 = min(s + t,     E - 1), i1 = min(s + t + 1, E - 1);
        int i2 = min(s + t + 2, E - 1), i3 = min(s + t + 3, E - 1);
        int e0 = col[i0], e1 = col[i1], e2 = col[i2], e3 = col[i3];
        uint2 v0 = Xg[(size_t)e0 * 32 + sl];
        uint2 v1 = Xg[(size_t)e1 * 32 + sl];
        uint2 v2 = Xg[(size_t)e2 * 32 + sl];
        uint2 v3 = Xg[(size_t)e3 * 32 + sl];
        if (!p0) { v0.x = 0; v0.y = 0; }
        if (!p1) { v1.x = 0; v1.y = 0; }
        if (!p2) { v2.x = 0; v2.y = 0; }
        if (!p3) { v3.x = 0; v3.y = 0; }
        a0  += b2f_lo(v0.x); a1  += b2f_hi(v0.x); a2  += b2f_lo(v0.y); a3  += b2f_hi(v0.y);
        c0f += b2f_lo(v1.x); c1f += b2f_hi(v1.x); c2f += b2f_lo(v1.y); c3f += b2f_hi(v1.y);
        a0  += b2f_lo(v2.x); a1  += b2f_hi(v2.x); a2  += b2f_lo(v2.y); a3  += b2f_hi(v2.y);
        c0f += b2f_lo(v3.x); c1f += b2f_hi(v3.x); c2f += b2f_lo(v3.y); c3f += b2f_hi(v3.y);
    }
    if (valid) {
        const float inv = dinv[node];
        uint2 o;
        o.x = f2b_rne((a0 + c0f) * inv) | (f2b_rne((a1 + c1f) * inv) << 16);
        o.y = f2b_rne((a2 + c2f) * inv) | (f2b_rne((a3 + c3f) * inv) << 16);
        *((uint2*)A + (size_t)node * 32 + sl) = o;
    }
}

// H2[i] = relu(mean_j Y[col[j]][0:192] + Y[i][192:384]). 2 nodes/wave, 32 lanes x 3 dwords, unroll 2.
__global__ void agg_cat192(const u16* __restrict__ Y, const int* __restrict__ rp,
                           const int* __restrict__ col, const float* __restrict__ dinv,
                           u16* __restrict__ H, int n, int E) {
    const int widx = (blockIdx.x * blockDim.x + threadIdx.x) >> 6;
    const int lane = threadIdx.x & 63;
    const int half = lane >> 5, sl = lane & 31;
    const int node = widx * 2 + half;
    const bool valid = node < n;
    const int s   = valid ? rp[node] : 0;
    const int deg = valid ? rp[node + 1] - s : 0;
    int m = deg;
    m = max(m, __shfl_xor(m, 32));
    const u32* Yw = (const u32*)Y;         // row = 192 dwords (384 bf16)
    float a[6] = {0, 0, 0, 0, 0, 0};
    float b[6] = {0, 0, 0, 0, 0, 0};
    for (int t = 0; t < m; t += 2) {
        bool p0 = t < deg, p1 = t + 1 < deg;
        int i0 = min(s + t, E - 1), i1 = min(s + t + 1, E - 1);
        int e0 = col[i0], e1 = col[i1];
        const u32* q0 = Yw + (size_t)e0 * 192 + sl * 3;
        const u32* q1 = Yw + (size_t)e1 * 192 + sl * 3;
        u32 w00 = q0[0], w01 = q0[1], w02 = q0[2];
        u32 w10 = q1[0], w11 = q1[1], w12 = q1[2];
        if (!p0) { w00 = 0; w01 = 0; w02 = 0; }
        if (!p1) { w10 = 0; w11 = 0; w12 = 0; }
        a[0] += b2f_lo(w00); a[1] += b2f_hi(w00);
        a[2] += b2f_lo(w01); a[3] += b2f_hi(w01);
        a[4] += b2f_lo(w02); a[5] += b2f_hi(w02);
        b[0] += b2f_lo(w10); b[1] += b2f_hi(w10);
        b[2] += b2f_lo(w11); b[3] += b2f_hi(w11);
        b[4] += b2f_lo(w12); b[5] += b2f_hi(w12);
    }
    if (valid) {
        const float inv = dinv[node];
        const u32* r = Yw + (size_t)node * 192 + 96 + sl * 3;
        u32 r0 = r[0], r1 = r[1], r2 = r[2];
        float o0 = fmaxf((a[0] + b[0]) * inv + b2f_lo(r0), 0.f);
        float o1 = fmaxf((a[1] + b[1]) * inv + b2f_hi(r0), 0.f);
        float o2 = fmaxf((a[2] + b[2]) * inv + b2f_lo(r1), 0.f);
        float o3 = fmaxf((a[3] + b[3]) * inv + b2f_hi(r1), 0.f);
        float o4 = fmaxf((a[4] + b[4]) * inv + b2f_lo(r2), 0.f);
        float o5 = fmaxf((a[5] + b[5]) * inv + b2f_hi(r2), 0.f);
        u32* Hw = (u32*)H + (size_t)node * 96 + sl * 3;
        Hw[0] = f2b_rne(o0) | (f2b_rne(o1) << 16);
        Hw[1] = f2b_rne(o2) | (f2b_rne(o3) << 16);
        Hw[2] = f2b_rne(o4) | (f2b_rne(o5) << 16);
    }
}

// out[i] = sigmoid(mean_j Y[col[j]][0:32] + Y[i][32:64]). 4 nodes/wave, 16 lanes x 1 dword, unroll 4.
__global__ void agg_cat32(const u16* __restrict__ Y, const int* __restrict__ rp,
                          const int* __restrict__ col, const float* __restrict__ dinv,
                          float* __restrict__ out, int n, int E) {
    const int widx = (blockIdx.x * blockDim.x + threadIdx.x) >> 6;
    const int lane = threadIdx.x & 63;
    const int grp = lane >> 4, sl = lane & 15;
    const int node = widx * 4 + grp;
    const bool valid = node < n;
    const int s   = valid ? rp[node] : 0;
    const int deg = valid ? rp[node + 1] - s : 0;
    int m = deg;
    m = max(m, __shfl_xor(m, 16));
    m = max(m, __shfl_xor(m, 32));
    const u32* Yw = (const u32*)Y;         // row = 32 dwords (64 bf16)
    float a0 = 0, a1 = 0, b0 = 0, b1 = 0;
    for (int t = 0; t < m; t += 4) {
        bool p0 = t < deg, p1 = t + 1 < deg, p2 = t + 2 < deg, p3 = t + 3 < deg;
        int i0 = min(s + t,     E - 1), i1 = min(s + t + 1, E - 1);
        int i2 = min(s + t + 2, E - 1), i3 = min(s + t + 3, E - 1);
        int e0 = col[i0], e1 = col[i1], e2 = col[i2], e3 = col[i3];
        u32 w0 = Yw[(size_t)e0 * 32 + sl];
        u32 w1 = Yw[(size_t)e1 * 32 + sl];
        u32 w2 = Yw[(size_t)e2 * 32 + sl];
        u32 w3 = Yw[(size_t)e3 * 32 + sl];
        if (!p0) w0 = 0;
        if (!p1) w1 = 0;
        if (!p2) w2 = 0;
        if (!p3) w3 = 0;
        a0 += b2f_lo(w0); a1 += b2f_hi(w0);
        b0 += b2f_lo(w1); b1 += b2f_hi(w1);
        a0 += b2f_lo(w2); a1 += b2f_hi(w2);
        b0 += b2f_lo(w3); b1 += b2f_hi(w3);
    }
    if (valid) {
        const float inv = dinv[node];
        u32 rv = Yw[(size_t)node * 32 + 16 + sl];
        float o0 = 1.f / (1.f + __expf(-((a0 + b0) * inv + b2f_lo(rv))));
        float o1 = 1.f / (1.f + __expf(-((a1 + b1) * inv + b2f_hi(rv))));
        *(float2*)(out + (size_t)node * 32 + sl * 2) = make_float2(o0, o1);
    }
}

// ---------------- MFMA GEMM (verified round 3, unchanged) ----------------
// out = act(A1@B1t^T [+ A2@B2t^T] + bias); A row-major bf16, Bt = [NDIM][KDIM] bf16.
template <int KDIM, int NDIM, int BN, int ACT, bool DUAL>
__global__ __launch_bounds__(256)
void gemm_mfma(const u16* __restrict__ A1, const u16* __restrict__ A2,
               const u16* __restrict__ B1t, const u16* __restrict__ B2t,
               const float* __restrict__ bias, u16* __restrict__ out, int M) {
    constexpr int BM = 128;
    constexpr int WR = (BN == 128) ? 2 : 4;
    constexpr int MF = BM / WR / 16;
    constexpr int NF = 4;
    __shared__ u16 As[BM * 64];
    __shared__ u16 Bs[BN * 64];

    const int row0 = blockIdx.x * BM;
    const int bn0  = blockIdx.y * BN;
    const int t    = threadIdx.x;
    const int wid  = t >> 6, ln = t & 63;
    const int ln15 = ln & 15, lg = ln >> 4;
    const int wr = (BN == 128) ? (wid >> 1) : wid;
    const int wc = (BN == 128) ? (wid & 1) : 0;
    const int wrow0 = wr * (BM / WR);
    const int wcol0 = wc * 64;

    f32x4 acc[MF][NF];
#pragma unroll
    for (int m = 0; m < MF; ++m)
#pragma unroll
        for (int nn = 0; nn < NF; ++nn) acc[m][nn] = (f32x4){0.f, 0.f, 0.f, 0.f};

#pragma unroll
    for (int s = 0; s < (DUAL ? 2 : 1); ++s) {
        const u16* A  = (DUAL && s) ? A2 : A1;
        const u16* Bt = (DUAL && s) ? B2t : B1t;
        for (int kt = 0; kt < KDIM / 64; ++kt) {
            const int k0 = kt * 64;
#pragma unroll
            for (int it = 0; it < 4; ++it) {
                int r = (t >> 3) + it * 32;
                int c = t & 7;
                int row = row0 + r; if (row >= M) row = M - 1;
                uint4 v = *(const uint4*)(A + (size_t)row * KDIM + k0 + c * 8);
                *(uint4*)(As + r * 64 + ((c ^ (r & 7)) * 8)) = v;
            }
#pragma unroll
            for (int it = 0; it < BN / 32; ++it) {
                int r = (t >> 3) + it * 32;
                int c = t & 7;
                uint4 v = *(const uint4*)(Bt + (size_t)(bn0 + r) * KDIM + k0 + c * 8);
                *(uint4*)(Bs + r * 64 + ((c ^ (r & 7)) * 8)) = v;
            }
            __syncthreads();
#pragma unroll
            for (int ks = 0; ks < 2; ++ks) {
                bf16x8 af[MF], bfr[NF];
#pragma unroll
                for (int m = 0; m < MF; ++m) {
                    int r  = wrow0 + m * 16 + ln15;
                    int ch = (ks * 4 + lg) ^ (r & 7);
                    af[m] = *(const bf16x8*)(As + r * 64 + ch * 8);
                }
#pragma unroll
                for (int nn = 0; nn < NF; ++nn) {
                    int r  = wcol0 + nn * 16 + ln15;
                    int ch = (ks * 4 + lg) ^ (r & 7);
                    bfr[nn] = *(const bf16x8*)(Bs + r * 64 + ch * 8);
                }
#pragma unroll
                for (int m = 0; m < MF; ++m)
#pragma unroll
                    for (int nn = 0; nn < NF; ++nn)
                        acc[m][nn] = __builtin_amdgcn_mfma_f32_16x16x32_bf16(
                            af[m], bfr[nn], acc[m][nn], 0, 0, 0);
            }
            __syncthreads();
        }
    }

#pragma unroll
    for (int nn = 0; nn < NF; ++nn) {
        const int col = bn0 + wcol0 + nn * 16 + ln15;
        const float bv = bias[col];
#pragma unroll
        for (int m = 0; m < MF; ++m) {
#pragma unroll
            for (int r = 0; r < 4; ++r) {
                int row = row0 + wrow0 + m * 16 + lg * 4 + r;
                if (row < M) {
                    float v = acc[m][nn][r] + bv;
                    if (ACT == 0) v = tanhf(v);
                    out[(size_t)row * NDIM + col] = (u16)f2b_rne(v);
                }
            }
        }
    }
}

// ---------------- launch ----------------

extern "C" void kernel_launch(void* const* d_in, const int* in_sizes, int n_in,
                              void* d_out, int out_size, void* d_ws, size_t ws_size,
                              hipStream_t stream) {
    const float* x   = (const float*)d_in[0];
    const int*   ei  = (const int*)  d_in[1];
    const float* W1l = (const float*)d_in[2];
    const float* W1r = (const float*)d_in[3];
    const float* b1  = (const float*)d_in[4];
    const float* W2l = (const float*)d_in[5];
    const float* W2r = (const float*)d_in[6];
    const float* b2  = (const float*)d_in[7];
    const float* W3l = (const float*)d_in[8];
    const float* W3r = (const float*)d_in[9];
    const float* b3  = (const float*)d_in[10];
    float* out = (float*)d_out;

    const int n = in_sizes[0] / 128;   // 100000
    const int E = in_sizes[1] / 2;     // 1600000
    const int* esrc = ei;
    const int* edst = ei + E;

    char* ws = (char*)d_ws;
    size_t off = 0;
    auto alloc = [&](size_t bytes) -> void* {
        void* p = ws + off;
        off += (bytes + 255) & ~(size_t)255;
        return p;
    };
    int*   rp    = (int*)  alloc((size_t)(n + 1) * 4);
    int*   cur   = (int*)  alloc((size_t)n * 4);
    int*   colx  = (int*)  alloc((size_t)E * 4);
    float* dinv  = (float*)alloc((size_t)n * 4);
    int*   bsum  = (int*)  alloc(512 * 4);
    u16*   W1lt  = (u16*)  alloc(256 * 128 * 2);
    u16*   W1rt  = (u16*)  alloc(256 * 128 * 2);
    u16*   W2t   = (u16*)  alloc(384 * 256 * 2);
    u16*   W3t   = (u16*)  alloc(64 * 192 * 2);
    float* b2cat = (float*)alloc(384 * 4);
    float* b3cat = (float*)alloc(64 * 4);
    u16*   Sa    = (u16*)  alloc((size_t)n * 384 * 2);  // xb+AGG1 -> Y2cat -> Y3cat
    u16*   Sb    = (u16*)  alloc((size_t)n * 256 * 2);  // H1 -> H2

    if (off > ws_size) return;   // insufficient workspace: fail cleanly (no fault)

    u16* xb   = Sa;
    u16* AGG1 = Sa + (size_t)n * 128;
    u16* Y2   = Sa;              // after xb/AGG1 are dead
    u16* Y3   = Sa;              // after Y2 is dead
    u16* H1   = Sb;
    u16* H2   = Sb;              // after H1 is dead

    const int NB = idiv(n, 256);
    const int GX = idiv(n, 128);

    // CSR
    hipMemsetAsync(cur, 0, (size_t)n * 4, stream);
    hist_kernel <<<idiv(E, 256), 256, 0, stream>>>(edst, E, n, cur);
    scan1_kernel<<<NB, 256, 0, stream>>>(cur, n, rp, bsum);
    scan2_kernel<<<1, 512, 0, stream>>>(bsum, NB);
    scan3_kernel<<<NB, 256, 0, stream>>>(rp, cur, dinv, bsum, n, E);
    fill_kernel <<<idiv(E, 256), 256, 0, stream>>>(esrc, edst, E, n, cur, colx);

    // prep: weights (bf16/transposed/concatenated) + bias cats + xb
    prep_all<<<idiv(176576, 256), 256, 0, stream>>>(
        W1l, W1r, W2l, W2r, W3l, W3r, b2, b3, W1lt, W1rt, W2t, W3t, b2cat, b3cat);
    cvt_x_kernel<<<idiv(n * 16, 256), 256, 0, stream>>>(x, xb, n * 16);

    // layer 1 (aggregate-first): H1 = tanh(AGG1@W1l + xb@W1r + b1)
    agg_mean128<<<idiv(n, 8), 256, 0, stream>>>(xb, rp, colx, dinv, AGG1, n, E);
    gemm_mfma<128, 256, 128, 0, true><<<dim3(GX, 2), 256, 0, stream>>>(
        AGG1, xb, W1lt, W1rt, b1, H1, n);

    // layer 2 (transform-first): Y2 = H1@[W2l|W2r] + [0|b2]; H2 = relu(agg(Y2l)+Y2r)
    gemm_mfma<256, 384, 128, -1, false><<<dim3(GX, 3), 256, 0, stream>>>(
        H1, (const u16*)nullptr, W2t, (const u16*)nullptr, b2cat, Y2, n);
    agg_cat192<<<idiv(n, 8), 256, 0, stream>>>(Y2, rp, colx, dinv, H2, n, E);

    // layer 3 (transform-first): Y3 = H2@[W3l|W3r] + [0|b3]; out = sigmoid(agg(Y3l)+Y3r)
    gemm_mfma<192, 64, 64, -1, false><<<dim3(GX, 1), 256, 0, stream>>>(
        H2, (const u16*)nullptr, W3t, (const u16*)nullptr, b3cat, Y3, n);
    agg_cat32<<<idiv(n, 16), 256, 0, stream>>>(Y3, rp, colx, dinv, out, n, E);
}

// Round 5
// 518.508 us; speedup vs baseline: 2.2926x; 1.0871x over previous
//
#include <hip/hip_runtime.h>
#include <math.h>

typedef unsigned short u16;
typedef unsigned int u32;
typedef __attribute__((ext_vector_type(8))) short bf16x8;
typedef __attribute__((ext_vector_type(4))) float f32x4;

static inline int idiv(int a, int b) { return (a + b - 1) / b; }

__device__ inline float b2f_lo(u32 w) { return __uint_as_float((w & 0xFFFFu) << 16); }
__device__ inline float b2f_hi(u32 w) { return __uint_as_float(w & 0xFFFF0000u); }
__device__ inline u32 f2b_rne(float f) {            // round-to-nearest-even bf16 bits
    u32 x = __float_as_uint(f);
    return (x + 0x7FFFu + ((x >> 16) & 1u)) >> 16;
}

// ---------------- CSR build ----------------
// hist/fill: XCD-range partitioned scatter. part = blockIdx&7 selects a dst
// range; under round-robin block->XCD dispatch all blocks of one part share an
// XCD, so their atomics/writes stay in that XCD's L2 (one writeback per line
// instead of one per store). Correct under ANY block->XCD mapping (each edge
// is processed by exactly one (chunk, part) block).

__global__ void hist_xcd(const int* __restrict__ dst, int E, int n, int* __restrict__ cnt) {
    const int part = blockIdx.x & 7;
    const int ch   = blockIdx.x >> 3;
    const int nch  = gridDim.x >> 3;
    const int lo = (int)((long long)n * part / 8);
    const int hi = (int)((long long)n * (part + 1) / 8);
    const int e0 = (int)((long long)E * ch / nch);
    const int e1 = (int)((long long)E * (ch + 1) / nch);
    for (int e = e0 + (int)threadIdx.x; e < e1; e += 256) {
        int d = dst[e];
        if (d >= lo && d < hi) atomicAdd(&cnt[d], 1);
    }
}

__global__ void fill_xcd(const int* __restrict__ src, const int* __restrict__ dst,
                         int E, int n, int* __restrict__ cur, int* __restrict__ col) {
    const int part = blockIdx.x & 7;
    const int ch   = blockIdx.x >> 3;
    const int nch  = gridDim.x >> 3;
    const int lo = (int)((long long)n * part / 8);
    const int hi = (int)((long long)n * (part + 1) / 8);
    const int e0 = (int)((long long)E * ch / nch);
    const int e1 = (int)((long long)E * (ch + 1) / nch);
    for (int e = e0 + (int)threadIdx.x; e < e1; e += 256) {
        int d = dst[e];
        int s = src[e];
        if (d >= lo && d < hi) {
            int p = atomicAdd(&cur[d], 1);
            if ((unsigned)s >= (unsigned)n) s = 0;
            col[p] = s;
        }
    }
}

__global__ void scan1_kernel(const int* __restrict__ cnt, int n,
                             int* __restrict__ rp, int* __restrict__ bsum) {
    __shared__ int s[256];
    int i = blockIdx.x * 256 + threadIdx.x;
    int v = (i < n) ? cnt[i] : 0;
    s[threadIdx.x] = v;
    __syncthreads();
    for (int off = 1; off < 256; off <<= 1) {
        int t = (threadIdx.x >= off) ? s[threadIdx.x - off] : 0;
        __syncthreads();
        s[threadIdx.x] += t;
        __syncthreads();
    }
    if (i < n) rp[i] = s[threadIdx.x] - v;
    if (threadIdx.x == 255) bsum[blockIdx.x] = s[255];
}

__global__ void scan2_kernel(int* __restrict__ bsum, int nb) {
    __shared__ int s[512];
    int v = ((int)threadIdx.x < nb) ? bsum[threadIdx.x] : 0;
    s[threadIdx.x] = v;
    __syncthreads();
    for (int off = 1; off < 512; off <<= 1) {
        int t = (threadIdx.x >= off) ? s[threadIdx.x - off] : 0;
        __syncthreads();
        s[threadIdx.x] += t;
        __syncthreads();
    }
    if ((int)threadIdx.x < nb) bsum[threadIdx.x] = s[threadIdx.x] - v;
}

__global__ void scan3_kernel(int* __restrict__ rp, int* __restrict__ cur,
                             float* __restrict__ dinv, const int* __restrict__ bsum,
                             int n, int E) {
    int i = blockIdx.x * 256 + threadIdx.x;
    if (i < n) {
        int c = cur[i];                    // still the count
        int v = rp[i] + bsum[blockIdx.x];
        rp[i]  = v;
        cur[i] = v;
        dinv[i] = 1.0f / (float)(c > 1 ? c : 1);
    }
    if (i == 0) rp[n] = E;
}

// ---------------- fused prep: all weight transposes + bias cats in one launch ----------------
// seg sizes: 32768,32768,49152,49152,6144,6144,384,64  (total 176576)
__global__ void prep_all(const float* __restrict__ W1l, const float* __restrict__ W1r,
                         const float* __restrict__ W2l, const float* __restrict__ W2r,
                         const float* __restrict__ W3l, const float* __restrict__ W3r,
                         const float* __restrict__ b2, const float* __restrict__ b3,
                         u16* __restrict__ W1lt, u16* __restrict__ W1rt,
                         u16* __restrict__ W2t, u16* __restrict__ W3t,
                         float* __restrict__ b2cat, float* __restrict__ b3cat) {
    int i = blockIdx.x * 256 + threadIdx.x;
    if (i < 32768) {                       // W1l^T: K=128, N=256
        int nn = i >> 7, k = i & 127;
        W1lt[i] = (u16)f2b_rne(W1l[k * 256 + nn]);
        return;
    }
    i -= 32768;
    if (i < 32768) {
        int nn = i >> 7, k = i & 127;
        W1rt[i] = (u16)f2b_rne(W1r[k * 256 + nn]);
        return;
    }
    i -= 32768;
    if (i < 49152) {                       // W2l^T: K=256, N=192
        int nn = i >> 8, k = i & 255;
        W2t[i] = (u16)f2b_rne(W2l[k * 192 + nn]);
        return;
    }
    i -= 49152;
    if (i < 49152) {
        int nn = i >> 8, k = i & 255;
        W2t[192 * 256 + i] = (u16)f2b_rne(W2r[k * 192 + nn]);
        return;
    }
    i -= 49152;
    if (i < 6144) {                        // W3l^T: K=192, N=32
        int nn = i / 192, k = i - nn * 192;
        W3t[i] = (u16)f2b_rne(W3l[k * 32 + nn]);
        return;
    }
    i -= 6144;
    if (i < 6144) {
        int nn = i / 192, k = i - nn * 192;
        W3t[32 * 192 + i] = (u16)f2b_rne(W3r[k * 32 + nn]);
        return;
    }
    i -= 6144;
    if (i < 384) { b2cat[i] = (i < 192) ? 0.f : b2[i - 192]; return; }
    i -= 384;
    if (i < 64)  { b3cat[i] = (i < 32) ? 0.f : b3[i - 32]; }
}

// xb = bf16(x), 8 elems/thread
__global__ void cvt_x_kernel(const float* __restrict__ x, u16* __restrict__ xb, int total8) {
    int i = blockIdx.x * 256 + threadIdx.x;
    if (i >= total8) return;
    const float4 a = *(const float4*)(x + (size_t)i * 8);
    const float4 b = *(const float4*)(x + (size_t)i * 8 + 4);
    uint4 o;
    o.x = f2b_rne(a.x) | (f2b_rne(a.y) << 16);
    o.y = f2b_rne(a.z) | (f2b_rne(a.w) << 16);
    o.z = f2b_rne(b.x) | (f2b_rne(b.y) << 16);
    o.w = f2b_rne(b.z) | (f2b_rne(b.w) << 16);
    *(uint4*)(xb + (size_t)i * 8) = o;
}

// ---------------- aggregation kernels (verified round 4) ----------------

// AGG1[i] = mean_j xb[col[j]]  (128 bf16). 2 nodes/wave, 32 lanes x uint2, unroll 4.
__global__ void agg_mean128(const u16* __restrict__ X, const int* __restrict__ rp,
                            const int* __restrict__ col, const float* __restrict__ dinv,
                            u16* __restrict__ A, int n, int E) {
    const int widx = (blockIdx.x * blockDim.x + threadIdx.x) >> 6;
    const int lane = threadIdx.x & 63;
    const int half = lane >> 5, sl = lane & 31;
    const int node = widx * 2 + half;
    const bool valid = node < n;
    const int s   = valid ? rp[node] : 0;
    const int deg = valid ? rp[node + 1] - s : 0;
    int m = deg;
    m = max(m, __shfl_xor(m, 32));
    const uint2* Xg = (const uint2*)X;     // row = 32 x uint2
    float a0 = 0, a1 = 0, a2 = 0, a3 = 0;
    float c0f = 0, c1f = 0, c2f = 0, c3f = 0;
    for (int t = 0; t < m; t += 4) {
        bool p0 = t < deg, p1 = t + 1 < deg, p2 = t + 2 < deg, p3 = t + 3 < deg;
        int i0 = min(s + t,     E - 1), i1 = min(s + t + 1, E - 1);
        int i2 = min(s + t + 2, E - 1), i3 = min(s + t + 3, E - 1);
        int e0 = col[i0], e1 = col[i1], e2 = col[i2], e3 = col[i3];
        uint2 v0 = Xg[(size_t)e0 * 32 + sl];
        uint2 v1 = Xg[(size_t)e1 * 32 + sl];
        uint2 v2 = Xg[(size_t)e2 * 32 + sl];
        uint2 v3 = Xg[(size_t)e3 * 32 + sl];
        if (!p0) { v0.x = 0; v0.y = 0; }
        if (!p1) { v1.x = 0; v1.y = 0; }
        if (!p2) { v2.x = 0; v2.y = 0; }
        if (!p3) { v3.x = 0; v3.y = 0; }
        a0  += b2f_lo(v0.x); a1  += b2f_hi(v0.x); a2  += b2f_lo(v0.y); a3  += b2f_hi(v0.y);
        c0f += b2f_lo(v1.x); c1f += b2f_hi(v1.x); c2f += b2f_lo(v1.y); c3f += b2f_hi(v1.y);
        a0  += b2f_lo(v2.x); a1  += b2f_hi(v2.x); a2  += b2f_lo(v2.y); a3  += b2f_hi(v2.y);
        c0f += b2f_lo(v3.x); c1f += b2f_hi(v3.x); c2f += b2f_lo(v3.y); c3f += b2f_hi(v3.y);
    }
    if (valid) {
        const float inv = dinv[node];
        uint2 o;
        o.x = f2b_rne((a0 + c0f) * inv) | (f2b_rne((a1 + c1f) * inv) << 16);
        o.y = f2b_rne((a2 + c2f) * inv) | (f2b_rne((a3 + c3f) * inv) << 16);
        *((uint2*)A + (size_t)node * 32 + sl) = o;
    }
}

// H2[i] = relu(mean_j Y[col[j]][0:192] + Y[i][192:384]). 2 nodes/wave, 32 lanes x 3 dwords, unroll 2.
__global__ void agg_cat192(const u16* __restrict__ Y, const int* __restrict__ rp,
                           const int* __restrict__ col, const float* __restrict__ dinv,
                           u16* __restrict__ H, int n, int E) {
    const int widx = (blockIdx.x * blockDim.x + threadIdx.x) >> 6;
    const int lane = threadIdx.x & 63;
    const int half = lane >> 5, sl = lane & 31;
    const int node = widx * 2 + half;
    const bool valid = node < n;
    const int s   = valid ? rp[node] : 0;
    const int deg = valid ? rp[node + 1] - s : 0;
    int m = deg;
    m = max(m, __shfl_xor(m, 32));
    const u32* Yw = (const u32*)Y;         // row = 192 dwords (384 bf16)
    float a[6] = {0, 0, 0, 0, 0, 0};
    float b[6] = {0, 0, 0, 0, 0, 0};
    for (int t = 0; t < m; t += 2) {
        bool p0 = t < deg, p1 = t + 1 < deg;
        int i0 = min(s + t, E - 1), i1 = min(s + t + 1, E - 1);
        int e0 = col[i0], e1 = col[i1];
        const u32* q0 = Yw + (size_t)e0 * 192 + sl * 3;
        const u32* q1 = Yw + (size_t)e1 * 192 + sl * 3;
        u32 w00 = q0[0], w01 = q0[1], w02 = q0[2];
        u32 w10 = q1[0], w11 = q1[1], w12 = q1[2];
        if (!p0) { w00 = 0; w01 = 0; w02 = 0; }
        if (!p1) { w10 = 0; w11 = 0; w12 = 0; }
        a[0] += b2f_lo(w00); a[1] += b2f_hi(w00);
        a[2] += b2f_lo(w01); a[3] += b2f_hi(w01);
        a[4] += b2f_lo(w02); a[5] += b2f_hi(w02);
        b[0] += b2f_lo(w10); b[1] += b2f_hi(w10);
        b[2] += b2f_lo(w11); b[3] += b2f_hi(w11);
        b[4] += b2f_lo(w12); b[5] += b2f_hi(w12);
    }
    if (valid) {
        const float inv = dinv[node];
        const u32* r = Yw + (size_t)node * 192 + 96 + sl * 3;
        u32 r0 = r[0], r1 = r[1], r2 = r[2];
        float o0 = fmaxf((a[0] + b[0]) * inv + b2f_lo(r0), 0.f);
        float o1 = fmaxf((a[1] + b[1]) * inv + b2f_hi(r0), 0.f);
        float o2 = fmaxf((a[2] + b[2]) * inv + b2f_lo(r1), 0.f);
        float o3 = fmaxf((a[3] + b[3]) * inv + b2f_hi(r1), 0.f);
        float o4 = fmaxf((a[4] + b[4]) * inv + b2f_lo(r2), 0.f);
        float o5 = fmaxf((a[5] + b[5]) * inv + b2f_hi(r2), 0.f);
        u32* Hw = (u32*)H + (size_t)node * 96 + sl * 3;
        Hw[0] = f2b_rne(o0) | (f2b_rne(o1) << 16);
        Hw[1] = f2b_rne(o2) | (f2b_rne(o3) << 16);
        Hw[2] = f2b_rne(o4) | (f2b_rne(o5) << 16);
    }
}

// out[i] = sigmoid(mean_j Y[col[j]][0:32] + Y[i][32:64]). 4 nodes/wave, 16 lanes x 1 dword, unroll 4.
__global__ void agg_cat32(const u16* __restrict__ Y, const int* __restrict__ rp,
                          const int* __restrict__ col, const float* __restrict__ dinv,
                          float* __restrict__ out, int n, int E) {
    const int widx = (blockIdx.x * blockDim.x + threadIdx.x) >> 6;
    const int lane = threadIdx.x & 63;
    const int grp = lane >> 4, sl = lane & 15;
    const int node = widx * 4 + grp;
    const bool valid = node < n;
    const int s   = valid ? rp[node] : 0;
    const int deg = valid ? rp[node + 1] - s : 0;
    int m = deg;
    m = max(m, __shfl_xor(m, 16));
    m = max(m, __shfl_xor(m, 32));
    const u32* Yw = (const u32*)Y;         // row = 32 dwords (64 bf16)
    float a0 = 0, a1 = 0, b0 = 0, b1 = 0;
    for (int t = 0; t < m; t += 4) {
        bool p0 = t < deg, p1 = t + 1 < deg, p2 = t + 2 < deg, p3 = t + 3 < deg;
        int i0 = min(s + t,     E - 1), i1 = min(s + t + 1, E - 1);
        int i2 = min(s + t + 2, E - 1), i3 = min(s + t + 3, E - 1);
        int e0 = col[i0], e1 = col[i1], e2 = col[i2], e3 = col[i3];
        u32 w0 = Yw[(size_t)e0 * 32 + sl];
        u32 w1 = Yw[(size_t)e1 * 32 + sl];
        u32 w2 = Yw[(size_t)e2 * 32 + sl];
        u32 w3 = Yw[(size_t)e3 * 32 + sl];
        if (!p0) w0 = 0;
        if (!p1) w1 = 0;
        if (!p2) w2 = 0;
        if (!p3) w3 = 0;
        a0 += b2f_lo(w0); a1 += b2f_hi(w0);
        b0 += b2f_lo(w1); b1 += b2f_hi(w1);
        a0 += b2f_lo(w2); a1 += b2f_hi(w2);
        b0 += b2f_lo(w3); b1 += b2f_hi(w3);
    }
    if (valid) {
        const float inv = dinv[node];
        u32 rv = Yw[(size_t)node * 32 + 16 + sl];
        float o0 = 1.f / (1.f + __expf(-((a0 + b0) * inv + b2f_lo(rv))));
        float o1 = 1.f / (1.f + __expf(-((a1 + b1) * inv + b2f_hi(rv))));
        *(float2*)(out + (size_t)node * 32 + sl * 2) = make_float2(o0, o1);
    }
}

// ---------------- MFMA GEMM (verified round 3, unchanged) ----------------
// out = act(A1@B1t^T [+ A2@B2t^T] + bias); A row-major bf16, Bt = [NDIM][KDIM] bf16.
template <int KDIM, int NDIM, int BN, int ACT, bool DUAL>
__global__ __launch_bounds__(256)
void gemm_mfma(const u16* __restrict__ A1, const u16* __restrict__ A2,
               const u16* __restrict__ B1t, const u16* __restrict__ B2t,
               const float* __restrict__ bias, u16* __restrict__ out, int M) {
    constexpr int BM = 128;
    constexpr int WR = (BN == 128) ? 2 : 4;
    constexpr int MF = BM / WR / 16;
    constexpr int NF = 4;
    __shared__ u16 As[BM * 64];
    __shared__ u16 Bs[BN * 64];

    const int row0 = blockIdx.x * BM;
    const int bn0  = blockIdx.y * BN;
    const int t    = threadIdx.x;
    const int wid  = t >> 6, ln = t & 63;
    const int ln15 = ln & 15, lg = ln >> 4;
    const int wr = (BN == 128) ? (wid >> 1) : wid;
    const int wc = (BN == 128) ? (wid & 1) : 0;
    const int wrow0 = wr * (BM / WR);
    const int wcol0 = wc * 64;

    f32x4 acc[MF][NF];
#pragma unroll
    for (int m = 0; m < MF; ++m)
#pragma unroll
        for (int nn = 0; nn < NF; ++nn) acc[m][nn] = (f32x4){0.f, 0.f, 0.f, 0.f};

#pragma unroll
    for (int s = 0; s < (DUAL ? 2 : 1); ++s) {
        const u16* A  = (DUAL && s) ? A2 : A1;
        const u16* Bt = (DUAL && s) ? B2t : B1t;
        for (int kt = 0; kt < KDIM / 64; ++kt) {
            const int k0 = kt * 64;
#pragma unroll
            for (int it = 0; it < 4; ++it) {
                int r = (t >> 3) + it * 32;
                int c = t & 7;
                int row = row0 + r; if (row >= M) row = M - 1;
                uint4 v = *(const uint4*)(A + (size_t)row * KDIM + k0 + c * 8);
                *(uint4*)(As + r * 64 + ((c ^ (r & 7)) * 8)) = v;
            }
#pragma unroll
            for (int it = 0; it < BN / 32; ++it) {
                int r = (t >> 3) + it * 32;
                int c = t & 7;
                uint4 v = *(const uint4*)(Bt + (size_t)(bn0 + r) * KDIM + k0 + c * 8);
                *(uint4*)(Bs + r * 64 + ((c ^ (r & 7)) * 8)) = v;
            }
            __syncthreads();
#pragma unroll
            for (int ks = 0; ks < 2; ++ks) {
                bf16x8 af[MF], bfr[NF];
#pragma unroll
                for (int m = 0; m < MF; ++m) {
                    int r  = wrow0 + m * 16 + ln15;
                    int ch = (ks * 4 + lg) ^ (r & 7);
                    af[m] = *(const bf16x8*)(As + r * 64 + ch * 8);
                }
#pragma unroll
                for (int nn = 0; nn < NF; ++nn) {
                    int r  = wcol0 + nn * 16 + ln15;
                    int ch = (ks * 4 + lg) ^ (r & 7);
                    bfr[nn] = *(const bf16x8*)(Bs + r * 64 + ch * 8);
                }
#pragma unroll
                for (int m = 0; m < MF; ++m)
#pragma unroll
                    for (int nn = 0; nn < NF; ++nn)
                        acc[m][nn] = __builtin_amdgcn_mfma_f32_16x16x32_bf16(
                            af[m], bfr[nn], acc[m][nn], 0, 0, 0);
            }
            __syncthreads();
        }
    }

#pragma unroll
    for (int nn = 0; nn < NF; ++nn) {
        const int col = bn0 + wcol0 + nn * 16 + ln15;
        const float bv = bias[col];
#pragma unroll
        for (int m = 0; m < MF; ++m) {
#pragma unroll
            for (int r = 0; r < 4; ++r) {
                int row = row0 + wrow0 + m * 16 + lg * 4 + r;
                if (row < M) {
                    float v = acc[m][nn][r] + bv;
                    if (ACT == 0) v = tanhf(v);
                    out[(size_t)row * NDIM + col] = (u16)f2b_rne(v);
                }
            }
        }
    }
}

// ---------------- launch ----------------

extern "C" void kernel_launch(void* const* d_in, const int* in_sizes, int n_in,
                              void* d_out, int out_size, void* d_ws, size_t ws_size,
                              hipStream_t stream) {
    const float* x   = (const float*)d_in[0];
    const int*   ei  = (const int*)  d_in[1];
    const float* W1l = (const float*)d_in[2];
    const float* W1r = (const float*)d_in[3];
    const float* b1  = (const float*)d_in[4];
    const float* W2l = (const float*)d_in[5];
    const float* W2r = (const float*)d_in[6];
    const float* b2  = (const float*)d_in[7];
    const float* W3l = (const float*)d_in[8];
    const float* W3r = (const float*)d_in[9];
    const float* b3  = (const float*)d_in[10];
    float* out = (float*)d_out;

    const int n = in_sizes[0] / 128;   // 100000
    const int E = in_sizes[1] / 2;     // 1600000
    const int* esrc = ei;
    const int* edst = ei + E;

    char* ws = (char*)d_ws;
    size_t off = 0;
    auto alloc = [&](size_t bytes) -> void* {
        void* p = ws + off;
        off += (bytes + 255) & ~(size_t)255;
        return p;
    };
    int*   rp    = (int*)  alloc((size_t)(n + 1) * 4);
    int*   cur   = (int*)  alloc((size_t)n * 4);
    int*   colx  = (int*)  alloc((size_t)E * 4);
    float* dinv  = (float*)alloc((size_t)n * 4);
    int*   bsum  = (int*)  alloc(512 * 4);
    u16*   W1lt  = (u16*)  alloc(256 * 128 * 2);
    u16*   W1rt  = (u16*)  alloc(256 * 128 * 2);
    u16*   W2t   = (u16*)  alloc(384 * 256 * 2);
    u16*   W3t   = (u16*)  alloc(64 * 192 * 2);
    float* b2cat = (float*)alloc(384 * 4);
    float* b3cat = (float*)alloc(64 * 4);
    u16*   Sa    = (u16*)  alloc((size_t)n * 384 * 2);  // xb+AGG1 -> Y2cat -> Y3cat
    u16*   Sb    = (u16*)  alloc((size_t)n * 256 * 2);  // H1 -> H2

    if (off > ws_size) return;   // insufficient workspace: fail cleanly (no fault)

    u16* xb   = Sa;
    u16* AGG1 = Sa + (size_t)n * 128;
    u16* Y2   = Sa;              // after xb/AGG1 are dead
    u16* Y3   = Sa;              // after Y2 is dead
    u16* H1   = Sb;
    u16* H2   = Sb;              // after H1 is dead

    const int NB = idiv(n, 256);
    const int GX = idiv(n, 128);
    const int SCAT_GRID = 8 * 192;   // 8 dst-ranges x 192 chunks

    // CSR
    hipMemsetAsync(cur, 0, (size_t)n * 4, stream);
    hist_xcd<<<SCAT_GRID, 256, 0, stream>>>(edst, E, n, cur);
    scan1_kernel<<<NB, 256, 0, stream>>>(cur, n, rp, bsum);
    scan2_kernel<<<1, 512, 0, stream>>>(bsum, NB);
    scan3_kernel<<<NB, 256, 0, stream>>>(rp, cur, dinv, bsum, n, E);
    fill_xcd<<<SCAT_GRID, 256, 0, stream>>>(esrc, edst, E, n, cur, colx);

    // prep: weights (bf16/transposed/concatenated) + bias cats + xb
    prep_all<<<idiv(176576, 256), 256, 0, stream>>>(
        W1l, W1r, W2l, W2r, W3l, W3r, b2, b3, W1lt, W1rt, W2t, W3t, b2cat, b3cat);
    cvt_x_kernel<<<idiv(n * 16, 256), 256, 0, stream>>>(x, xb, n * 16);

    // layer 1 (aggregate-first): H1 = tanh(AGG1@W1l + xb@W1r + b1)
    agg_mean128<<<idiv(n, 8), 256, 0, stream>>>(xb, rp, colx, dinv, AGG1, n, E);
    gemm_mfma<128, 256, 128, 0, true><<<dim3(GX, 2), 256, 0, stream>>>(
        AGG1, xb, W1lt, W1rt, b1, H1, n);

    // layer 2 (transform-first): Y2 = H1@[W2l|W2r] + [0|b2]; H2 = relu(agg(Y2l)+Y2r)
    gemm_mfma<256, 384, 128, -1, false><<<dim3(GX, 3), 256, 0, stream>>>(
        H1, (const u16*)nullptr, W2t, (const u16*)nullptr, b2cat, Y2, n);
    agg_cat192<<<idiv(n, 8), 256, 0, stream>>>(Y2, rp, colx, dinv, H2, n, E);

    // layer 3 (transform-first): Y3 = H2@[W3l|W3r] + [0|b3]; out = sigmoid(agg(Y3l)+Y3r)
    gemm_mfma<192, 64, 64, -1, false><<<dim3(GX, 1), 256, 0, stream>>>(
        H2, (const u16*)nullptr, W3t, (const u16*)nullptr, b3cat, Y3, n);
    agg_cat32<<<idiv(n, 16), 256, 0, stream>>>(Y3, rp, colx, dinv, out, n, E);
}

// Round 6
// 517.190 us; speedup vs baseline: 2.2984x; 1.0025x over previous
//
#include <hip/hip_runtime.h>
#include <math.h>

typedef unsigned short u16;
typedef unsigned int u32;
typedef __attribute__((ext_vector_type(8))) short bf16x8;
typedef __attribute__((ext_vector_type(4))) float f32x4;

static inline int idiv(int a, int b) { return (a + b - 1) / b; }

__device__ inline float b2f_lo(u32 w) { return __uint_as_float((w & 0xFFFFu) << 16); }
__device__ inline float b2f_hi(u32 w) { return __uint_as_float(w & 0xFFFF0000u); }
__device__ inline u32 f2b_rne(float f) {            // round-to-nearest-even bf16 bits
    u32 x = __float_as_uint(f);
    return (x + 0x7FFFu + ((x >> 16) & 1u)) >> 16;
}

// async global->LDS, 16 B per lane. LDS dest = wave-uniform base + lane*16
// (pass the same base in all lanes); global src address is PER-LANE.
__device__ __forceinline__ void g2lds16(const u16* gsrc, u16* ldsbase) {
    __builtin_amdgcn_global_load_lds(
        (const __attribute__((address_space(1))) u32*)gsrc,
        (__attribute__((address_space(3))) u32*)ldsbase, 16, 0, 0);
}

// ---------------- CSR build (verified round 5) ----------------

__global__ void hist_xcd(const int* __restrict__ dst, int E, int n, int* __restrict__ cnt) {
    const int part = blockIdx.x & 7;
    const int ch   = blockIdx.x >> 3;
    const int nch  = gridDim.x >> 3;
    const int lo = (int)((long long)n * part / 8);
    const int hi = (int)((long long)n * (part + 1) / 8);
    const int e0 = (int)((long long)E * ch / nch);
    const int e1 = (int)((long long)E * (ch + 1) / nch);
    for (int e = e0 + (int)threadIdx.x; e < e1; e += 256) {
        int d = dst[e];
        if (d >= lo && d < hi) atomicAdd(&cnt[d], 1);
    }
}

__global__ void fill_xcd(const int* __restrict__ src, const int* __restrict__ dst,
                         int E, int n, int* __restrict__ cur, int* __restrict__ col) {
    const int part = blockIdx.x & 7;
    const int ch   = blockIdx.x >> 3;
    const int nch  = gridDim.x >> 3;
    const int lo = (int)((long long)n * part / 8);
    const int hi = (int)((long long)n * (part + 1) / 8);
    const int e0 = (int)((long long)E * ch / nch);
    const int e1 = (int)((long long)E * (ch + 1) / nch);
    for (int e = e0 + (int)threadIdx.x; e < e1; e += 256) {
        int d = dst[e];
        int s = src[e];
        if (d >= lo && d < hi) {
            int p = atomicAdd(&cur[d], 1);
            if ((unsigned)s >= (unsigned)n) s = 0;
            col[p] = s;
        }
    }
}

__global__ void scan1_kernel(const int* __restrict__ cnt, int n,
                             int* __restrict__ rp, int* __restrict__ bsum) {
    __shared__ int s[256];
    int i = blockIdx.x * 256 + threadIdx.x;
    int v = (i < n) ? cnt[i] : 0;
    s[threadIdx.x] = v;
    __syncthreads();
    for (int off = 1; off < 256; off <<= 1) {
        int t = (threadIdx.x >= off) ? s[threadIdx.x - off] : 0;
        __syncthreads();
        s[threadIdx.x] += t;
        __syncthreads();
    }
    if (i < n) rp[i] = s[threadIdx.x] - v;
    if (threadIdx.x == 255) bsum[blockIdx.x] = s[255];
}

__global__ void scan2_kernel(int* __restrict__ bsum, int nb) {
    __shared__ int s[512];
    int v = ((int)threadIdx.x < nb) ? bsum[threadIdx.x] : 0;
    s[threadIdx.x] = v;
    __syncthreads();
    for (int off = 1; off < 512; off <<= 1) {
        int t = (threadIdx.x >= off) ? s[threadIdx.x - off] : 0;
        __syncthreads();
        s[threadIdx.x] += t;
        __syncthreads();
    }
    if ((int)threadIdx.x < nb) bsum[threadIdx.x] = s[threadIdx.x] - v;
}

__global__ void scan3_kernel(int* __restrict__ rp, int* __restrict__ cur,
                             float* __restrict__ dinv, const int* __restrict__ bsum,
                             int n, int E) {
    int i = blockIdx.x * 256 + threadIdx.x;
    if (i < n) {
        int c = cur[i];                    // still the count
        int v = rp[i] + bsum[blockIdx.x];
        rp[i]  = v;
        cur[i] = v;
        dinv[i] = 1.0f / (float)(c > 1 ? c : 1);
    }
    if (i == 0) rp[n] = E;
}

// ---------------- fused prep (verified round 4) ----------------
__global__ void prep_all(const float* __restrict__ W1l, const float* __restrict__ W1r,
                         const float* __restrict__ W2l, const float* __restrict__ W2r,
                         const float* __restrict__ W3l, const float* __restrict__ W3r,
                         const float* __restrict__ b2, const float* __restrict__ b3,
                         u16* __restrict__ W1lt, u16* __restrict__ W1rt,
                         u16* __restrict__ W2t, u16* __restrict__ W3t,
                         float* __restrict__ b2cat, float* __restrict__ b3cat) {
    int i = blockIdx.x * 256 + threadIdx.x;
    if (i < 32768) {                       // W1l^T: K=128, N=256
        int nn = i >> 7, k = i & 127;
        W1lt[i] = (u16)f2b_rne(W1l[k * 256 + nn]);
        return;
    }
    i -= 32768;
    if (i < 32768) {
        int nn = i >> 7, k = i & 127;
        W1rt[i] = (u16)f2b_rne(W1r[k * 256 + nn]);
        return;
    }
    i -= 32768;
    if (i < 49152) {                       // W2l^T: K=256, N=192
        int nn = i >> 8, k = i & 255;
        W2t[i] = (u16)f2b_rne(W2l[k * 192 + nn]);
        return;
    }
    i -= 49152;
    if (i < 49152) {
        int nn = i >> 8, k = i & 255;
        W2t[192 * 256 + i] = (u16)f2b_rne(W2r[k * 192 + nn]);
        return;
    }
    i -= 49152;
    if (i < 6144) {                        // W3l^T: K=192, N=32
        int nn = i / 192, k = i - nn * 192;
        W3t[i] = (u16)f2b_rne(W3l[k * 32 + nn]);
        return;
    }
    i -= 6144;
    if (i < 6144) {
        int nn = i / 192, k = i - nn * 192;
        W3t[32 * 192 + i] = (u16)f2b_rne(W3r[k * 32 + nn]);
        return;
    }
    i -= 6144;
    if (i < 384) { b2cat[i] = (i < 192) ? 0.f : b2[i - 192]; return; }
    i -= 384;
    if (i < 64)  { b3cat[i] = (i < 32) ? 0.f : b3[i - 32]; }
}

// xb = bf16(x), 8 elems/thread
__global__ void cvt_x_kernel(const float* __restrict__ x, u16* __restrict__ xb, int total8) {
    int i = blockIdx.x * 256 + threadIdx.x;
    if (i >= total8) return;
    const float4 a = *(const float4*)(x + (size_t)i * 8);
    const float4 b = *(const float4*)(x + (size_t)i * 8 + 4);
    uint4 o;
    o.x = f2b_rne(a.x) | (f2b_rne(a.y) << 16);
    o.y = f2b_rne(a.z) | (f2b_rne(a.w) << 16);
    o.z = f2b_rne(b.x) | (f2b_rne(b.y) << 16);
    o.w = f2b_rne(b.z) | (f2b_rne(b.w) << 16);
    *(uint4*)(xb + (size_t)i * 8) = o;
}

// ---------------- aggregation kernels ----------------

// AGG1[i] = mean_j xb[col[j]]  (128 bf16). 2 nodes/wave, 32 lanes x uint2, unroll 4. (verified r4)
__global__ void agg_mean128(const u16* __restrict__ X, const int* __restrict__ rp,
                            const int* __restrict__ col, const float* __restrict__ dinv,
                            u16* __restrict__ A, int n, int E) {
    const int widx = (blockIdx.x * blockDim.x + threadIdx.x) >> 6;
    const int lane = threadIdx.x & 63;
    const int half = lane >> 5, sl = lane & 31;
    const int node = widx * 2 + half;
    const bool valid = node < n;
    const int s   = valid ? rp[node] : 0;
    const int deg = valid ? rp[node + 1] - s : 0;
    int m = deg;
    m = max(m, __shfl_xor(m, 32));
    const uint2* Xg = (const uint2*)X;     // row = 32 x uint2
    float a0 = 0, a1 = 0, a2 = 0, a3 = 0;
    float c0f = 0, c1f = 0, c2f = 0, c3f = 0;
    for (int t = 0; t < m; t += 4) {
        bool p0 = t < deg, p1 = t + 1 < deg, p2 = t + 2 < deg, p3 = t + 3 < deg;
        int i0 = min(s + t,     E - 1), i1 = min(s + t + 1, E - 1);
        int i2 = min(s + t + 2, E - 1), i3 = min(s + t + 3, E - 1);
        int e0 = col[i0], e1 = col[i1], e2 = col[i2], e3 = col[i3];
        uint2 v0 = Xg[(size_t)e0 * 32 + sl];
        uint2 v1 = Xg[(size_t)e1 * 32 + sl];
        uint2 v2 = Xg[(size_t)e2 * 32 + sl];
        uint2 v3 = Xg[(size_t)e3 * 32 + sl];
        if (!p0) { v0.x = 0; v0.y = 0; }
        if (!p1) { v1.x = 0; v1.y = 0; }
        if (!p2) { v2.x = 0; v2.y = 0; }
        if (!p3) { v3.x = 0; v3.y = 0; }
        a0  += b2f_lo(v0.x); a1  += b2f_hi(v0.x); a2  += b2f_lo(v0.y); a3  += b2f_hi(v0.y);
        c0f += b2f_lo(v1.x); c1f += b2f_hi(v1.x); c2f += b2f_lo(v1.y); c3f += b2f_hi(v1.y);
        a0  += b2f_lo(v2.x); a1  += b2f_hi(v2.x); a2  += b2f_lo(v2.y); a3  += b2f_hi(v2.y);
        c0f += b2f_lo(v3.x); c1f += b2f_hi(v3.x); c2f += b2f_lo(v3.y); c3f += b2f_hi(v3.y);
    }
    if (valid) {
        const float inv = dinv[node];
        uint2 o;
        o.x = f2b_rne((a0 + c0f) * inv) | (f2b_rne((a1 + c1f) * inv) << 16);
        o.y = f2b_rne((a2 + c2f) * inv) | (f2b_rne((a3 + c3f) * inv) << 16);
        *((uint2*)A + (size_t)node * 32 + sl) = o;
    }
}

// H2[i] = relu(mean_j Y[col[j]][0:192] + Y[i][192:384]).
// 2 nodes/wave, 32 lanes; per edge-row: uint2 @8*sl (cols 4sl..4sl+3) +
// dword @256+4*sl (cols 128+2sl..+1) -> 2 coalesced requests. Unroll 3.
__global__ void agg_cat192(const u16* __restrict__ Y, const int* __restrict__ rp,
                           const int* __restrict__ col, const float* __restrict__ dinv,
                           u16* __restrict__ H, int n, int E) {
    const int widx = (blockIdx.x * blockDim.x + threadIdx.x) >> 6;
    const int lane = threadIdx.x & 63;
    const int half = lane >> 5, sl = lane & 31;
    const int node = widx * 2 + half;
    const bool valid = node < n;
    const int s   = valid ? rp[node] : 0;
    const int deg = valid ? rp[node + 1] - s : 0;
    int m = deg;
    m = max(m, __shfl_xor(m, 32));
    const char* Yb = (const char*)Y;       // row stride 768 B
    float a[6] = {0, 0, 0, 0, 0, 0};
    float b[6] = {0, 0, 0, 0, 0, 0};
    float c[6] = {0, 0, 0, 0, 0, 0};
    const int off8 = 8 * sl, off4 = 256 + 4 * sl;
    for (int t = 0; t < m; t += 3) {
        bool p0 = t < deg, p1 = t + 1 < deg, p2 = t + 2 < deg;
        int i0 = min(s + t, E - 1), i1 = min(s + t + 1, E - 1), i2 = min(s + t + 2, E - 1);
        int e0 = col[i0], e1 = col[i1], e2 = col[i2];
        const char* r0 = Yb + (size_t)e0 * 768;
        const char* r1 = Yb + (size_t)e1 * 768;
        const char* r2 = Yb + (size_t)e2 * 768;
        uint2 u0 = *(const uint2*)(r0 + off8);
        uint2 u1 = *(const uint2*)(r1 + off8);
        uint2 u2 = *(const uint2*)(r2 + off8);
        u32 d0 = *(const u32*)(r0 + off4);
        u32 d1 = *(const u32*)(r1 + off4);
        u32 d2 = *(const u32*)(r2 + off4);
        if (!p0) { u0.x = 0; u0.y = 0; d0 = 0; }
        if (!p1) { u1.x = 0; u1.y = 0; d1 = 0; }
        if (!p2) { u2.x = 0; u2.y = 0; d2 = 0; }
        a[0] += b2f_lo(u0.x); a[1] += b2f_hi(u0.x);
        a[2] += b2f_lo(u0.y); a[3] += b2f_hi(u0.y);
        a[4] += b2f_lo(d0);   a[5] += b2f_hi(d0);
        b[0] += b2f_lo(u1.x); b[1] += b2f_hi(u1.x);
        b[2] += b2f_lo(u1.y); b[3] += b2f_hi(u1.y);
        b[4] += b2f_lo(d1);   b[5] += b2f_hi(d1);
        c[0] += b2f_lo(u2.x); c[1] += b2f_hi(u2.x);
        c[2] += b2f_lo(u2.y); c[3] += b2f_hi(u2.y);
        c[4] += b2f_lo(d2);   c[5] += b2f_hi(d2);
    }
    if (valid) {
        const float inv = dinv[node];
        const char* rs = Yb + (size_t)node * 768 + 384;   // self: cols 192..383
        uint2 ru = *(const uint2*)(rs + off8);
        u32   rd = *(const u32*)(rs + off4);
        float o0 = fmaxf((a[0] + b[0] + c[0]) * inv + b2f_lo(ru.x), 0.f);
        float o1 = fmaxf((a[1] + b[1] + c[1]) * inv + b2f_hi(ru.x), 0.f);
        float o2 = fmaxf((a[2] + b[2] + c[2]) * inv + b2f_lo(ru.y), 0.f);
        float o3 = fmaxf((a[3] + b[3] + c[3]) * inv + b2f_hi(ru.y), 0.f);
        float o4 = fmaxf((a[4] + b[4] + c[4]) * inv + b2f_lo(rd), 0.f);
        float o5 = fmaxf((a[5] + b[5] + c[5]) * inv + b2f_hi(rd), 0.f);
        char* hb = (char*)H + (size_t)node * 384;
        uint2 ou; ou.x = f2b_rne(o0) | (f2b_rne(o1) << 16);
        ou.y = f2b_rne(o2) | (f2b_rne(o3) << 16);
        *(uint2*)(hb + off8) = ou;
        *(u32*)(hb + off4) = f2b_rne(o4) | (f2b_rne(o5) << 16);
    }
}

// out[i] = sigmoid(mean_j Y[col[j]][0:32] + Y[i][32:64]). 4 nodes/wave, unroll 4. (verified r4)
__global__ void agg_cat32(const u16* __restrict__ Y, const int* __restrict__ rp,
                          const int* __restrict__ col, const float* __restrict__ dinv,
                          float* __restrict__ out, int n, int E) {
    const int widx = (blockIdx.x * blockDim.x + threadIdx.x) >> 6;
    const int lane = threadIdx.x & 63;
    const int grp = lane >> 4, sl = lane & 15;
    const int node = widx * 4 + grp;
    const bool valid = node < n;
    const int s   = valid ? rp[node] : 0;
    const int deg = valid ? rp[node + 1] - s : 0;
    int m = deg;
    m = max(m, __shfl_xor(m, 16));
    m = max(m, __shfl_xor(m, 32));
    const u32* Yw = (const u32*)Y;         // row = 32 dwords (64 bf16)
    float a0 = 0, a1 = 0, b0 = 0, b1 = 0;
    for (int t = 0; t < m; t += 4) {
        bool p0 = t < deg, p1 = t + 1 < deg, p2 = t + 2 < deg, p3 = t + 3 < deg;
        int i0 = min(s + t,     E - 1), i1 = min(s + t + 1, E - 1);
        int i2 = min(s + t + 2, E - 1), i3 = min(s + t + 3, E - 1);
        int e0 = col[i0], e1 = col[i1], e2 = col[i2], e3 = col[i3];
        u32 w0 = Yw[(size_t)e0 * 32 + sl];
        u32 w1 = Yw[(size_t)e1 * 32 + sl];
        u32 w2 = Yw[(size_t)e2 * 32 + sl];
        u32 w3 = Yw[(size_t)e3 * 32 + sl];
        if (!p0) w0 = 0;
        if (!p1) w1 = 0;
        if (!p2) w2 = 0;
        if (!p3) w3 = 0;
        a0 += b2f_lo(w0); a1 += b2f_hi(w0);
        b0 += b2f_lo(w1); b1 += b2f_hi(w1);
        a0 += b2f_lo(w2); a1 += b2f_hi(w2);
        b0 += b2f_lo(w3); b1 += b2f_hi(w3);
    }
    if (valid) {
        const float inv = dinv[node];
        u32 rv = Yw[(size_t)node * 32 + 16 + sl];
        float o0 = 1.f / (1.f + __expf(-((a0 + b0) * inv + b2f_lo(rv))));
        float o1 = 1.f / (1.f + __expf(-((a1 + b1) * inv + b2f_hi(rv))));
        *(float2*)(out + (size_t)node * 32 + sl * 2) = make_float2(o0, o1);
    }
}

// ---------------- MFMA GEMM with global_load_lds staging ----------------
// out = act(A1@B1t^T [+ A2@B2t^T] + bias); A row-major bf16, Bt = [NDIM][KDIM] bf16.
// LDS tiles [rows][64] bf16, XOR-swizzled chunks (chunk ^= row&7). Staging via
// global_load_lds width-16: LDS dest linear (wave-uniform base + lane*16);
// swizzle folded into per-lane GLOBAL source chunk (rloc&7 == lane>>3).
template <int KDIM, int NDIM, int BN, int ACT, bool DUAL>
__global__ __launch_bounds__(256)
void gemm_mfma(const u16* __restrict__ A1, const u16* __restrict__ A2,
               const u16* __restrict__ B1t, const u16* __restrict__ B2t,
               const float* __restrict__ bias, u16* __restrict__ out, int M) {
    constexpr int BM = 128;
    constexpr int WR = (BN == 128) ? 2 : 4;
    constexpr int MF = BM / WR / 16;
    constexpr int NF = 4;
    __shared__ u16 As[BM * 64];
    __shared__ u16 Bs[BN * 64];

    const int row0 = blockIdx.x * BM;
    const int bn0  = blockIdx.y * BN;
    const int t    = threadIdx.x;
    const int wid  = t >> 6, ln = t & 63;
    const int lr   = ln >> 3;          // row-within-8 (== swizzle key)
    const int lc   = ln & 7;           // chunk
    const int ln15 = ln & 15, lg = ln >> 4;
    const int wr = (BN == 128) ? (wid >> 1) : wid;
    const int wc = (BN == 128) ? (wid & 1) : 0;
    const int wrow0 = wr * (BM / WR);
    const int wcol0 = wc * 64;
    const int swch  = (lc ^ lr) * 8;   // pre-swizzled source chunk offset (elems)

    f32x4 acc[MF][NF];
#pragma unroll
    for (int m = 0; m < MF; ++m)
#pragma unroll
        for (int nn = 0; nn < NF; ++nn) acc[m][nn] = (f32x4){0.f, 0.f, 0.f, 0.f};

#pragma unroll
    for (int s = 0; s < (DUAL ? 2 : 1); ++s) {
        const u16* A  = (DUAL && s) ? A2 : A1;
        const u16* Bt = (DUAL && s) ? B2t : B1t;
        for (int kt = 0; kt < KDIM / 64; ++kt) {
            const int k0 = kt * 64;
            // A tile: 128 rows; wave w, iter it stages rows [it*32+8w, +8)
#pragma unroll
            for (int it = 0; it < 4; ++it) {
                int rloc = it * 32 + 8 * wid + lr;
                int grow = row0 + rloc; if (grow >= M) grow = M - 1;
                g2lds16(A + (size_t)grow * KDIM + k0 + swch,
                        As + (it * 32 + 8 * wid) * 64);
            }
            // B tile: BN rows
#pragma unroll
            for (int it = 0; it < BN / 32; ++it) {
                int rloc = it * 32 + 8 * wid + lr;
                g2lds16(Bt + (size_t)(bn0 + rloc) * KDIM + k0 + swch,
                        Bs + (it * 32 + 8 * wid) * 64);
            }
            __syncthreads();   // drains vmcnt for global_load_lds
#pragma unroll
            for (int ks = 0; ks < 2; ++ks) {
                bf16x8 af[MF], bfr[NF];
#pragma unroll
                for (int m = 0; m < MF; ++m) {
                    int r  = wrow0 + m * 16 + ln15;
                    int ch = (ks * 4 + lg) ^ (r & 7);
                    af[m] = *(const bf16x8*)(As + r * 64 + ch * 8);
                }
#pragma unroll
                for (int nn = 0; nn < NF; ++nn) {
                    int r  = wcol0 + nn * 16 + ln15;
                    int ch = (ks * 4 + lg) ^ (r & 7);
                    bfr[nn] = *(const bf16x8*)(Bs + r * 64 + ch * 8);
                }
#pragma unroll
                for (int m = 0; m < MF; ++m)
#pragma unroll
                    for (int nn = 0; nn < NF; ++nn)
                        acc[m][nn] = __builtin_amdgcn_mfma_f32_16x16x32_bf16(
                            af[m], bfr[nn], acc[m][nn], 0, 0, 0);
            }
            __syncthreads();
        }
    }

    // epilogue: C/D layout col = lane&15, row = (lane>>4)*4 + reg
#pragma unroll
    for (int nn = 0; nn < NF; ++nn) {
        const int col = bn0 + wcol0 + nn * 16 + ln15;
        const float bv = bias[col];
#pragma unroll
        for (int m = 0; m < MF; ++m) {
#pragma unroll
            for (int r = 0; r < 4; ++r) {
                int row = row0 + wrow0 + m * 16 + lg * 4 + r;
                if (row < M) {
                    float v = acc[m][nn][r] + bv;
                    if (ACT == 0) v = tanhf(v);
                    out[(size_t)row * NDIM + col] = (u16)f2b_rne(v);
                }
            }
        }
    }
}

// ---------------- launch ----------------

extern "C" void kernel_launch(void* const* d_in, const int* in_sizes, int n_in,
                              void* d_out, int out_size, void* d_ws, size_t ws_size,
                              hipStream_t stream) {
    const float* x   = (const float*)d_in[0];
    const int*   ei  = (const int*)  d_in[1];
    const float* W1l = (const float*)d_in[2];
    const float* W1r = (const float*)d_in[3];
    const float* b1  = (const float*)d_in[4];
    const float* W2l = (const float*)d_in[5];
    const float* W2r = (const float*)d_in[6];
    const float* b2  = (const float*)d_in[7];
    const float* W3l = (const float*)d_in[8];
    const float* W3r = (const float*)d_in[9];
    const float* b3  = (const float*)d_in[10];
    float* out = (float*)d_out;

    const int n = in_sizes[0] / 128;   // 100000
    const int E = in_sizes[1] / 2;     // 1600000
    const int* esrc = ei;
    const int* edst = ei + E;

    char* ws = (char*)d_ws;
    size_t off = 0;
    auto alloc = [&](size_t bytes) -> void* {
        void* p = ws + off;
        off += (bytes + 255) & ~(size_t)255;
        return p;
    };
    int*   rp    = (int*)  alloc((size_t)(n + 1) * 4);
    int*   cur   = (int*)  alloc((size_t)n * 4);
    int*   colx  = (int*)  alloc((size_t)E * 4);
    float* dinv  = (float*)alloc((size_t)n * 4);
    int*   bsum  = (int*)  alloc(512 * 4);
    u16*   W1lt  = (u16*)  alloc(256 * 128 * 2);
    u16*   W1rt  = (u16*)  alloc(256 * 128 * 2);
    u16*   W2t   = (u16*)  alloc(384 * 256 * 2);
    u16*   W3t   = (u16*)  alloc(64 * 192 * 2);
    float* b2cat = (float*)alloc(384 * 4);
    float* b3cat = (float*)alloc(64 * 4);
    u16*   Sa    = (u16*)  alloc((size_t)n * 384 * 2);  // xb+AGG1 -> Y2cat -> Y3cat
    u16*   Sb    = (u16*)  alloc((size_t)n * 256 * 2);  // H1 -> H2

    if (off > ws_size) return;   // insufficient workspace: fail cleanly (no fault)

    u16* xb   = Sa;
    u16* AGG1 = Sa + (size_t)n * 128;
    u16* Y2   = Sa;              // after xb/AGG1 are dead
    u16* Y3   = Sa;              // after Y2 is dead
    u16* H1   = Sb;
    u16* H2   = Sb;              // after H1 is dead

    const int NB = idiv(n, 256);
    const int GX = idiv(n, 128);
    const int SCAT_GRID = 8 * 192;   // 8 dst-ranges x 192 chunks

    // CSR
    hipMemsetAsync(cur, 0, (size_t)n * 4, stream);
    hist_xcd<<<SCAT_GRID, 256, 0, stream>>>(edst, E, n, cur);
    scan1_kernel<<<NB, 256, 0, stream>>>(cur, n, rp, bsum);
    scan2_kernel<<<1, 512, 0, stream>>>(bsum, NB);
    scan3_kernel<<<NB, 256, 0, stream>>>(rp, cur, dinv, bsum, n, E);
    fill_xcd<<<SCAT_GRID, 256, 0, stream>>>(esrc, edst, E, n, cur, colx);

    // prep: weights (bf16/transposed/concatenated) + bias cats + xb
    prep_all<<<idiv(176576, 256), 256, 0, stream>>>(
        W1l, W1r, W2l, W2r, W3l, W3r, b2, b3, W1lt, W1rt, W2t, W3t, b2cat, b3cat);
    cvt_x_kernel<<<idiv(n * 16, 256), 256, 0, stream>>>(x, xb, n * 16);

    // layer 1 (aggregate-first): H1 = tanh(AGG1@W1l + xb@W1r + b1)
    agg_mean128<<<idiv(n, 8), 256, 0, stream>>>(xb, rp, colx, dinv, AGG1, n, E);
    gemm_mfma<128, 256, 128, 0, true><<<dim3(GX, 2), 256, 0, stream>>>(
        AGG1, xb, W1lt, W1rt, b1, H1, n);

    // layer 2 (transform-first): Y2 = H1@[W2l|W2r] + [0|b2]; H2 = relu(agg(Y2l)+Y2r)
    gemm_mfma<256, 384, 128, -1, false><<<dim3(GX, 3), 256, 0, stream>>>(
        H1, (const u16*)nullptr, W2t, (const u16*)nullptr, b2cat, Y2, n);
    agg_cat192<<<idiv(n, 8), 256, 0, stream>>>(Y2, rp, colx, dinv, H2, n, E);

    // layer 3 (transform-first): Y3 = H2@[W3l|W3r] + [0|b3]; out = sigmoid(agg(Y3l)+Y3r)
    gemm_mfma<192, 64, 64, -1, false><<<dim3(GX, 1), 256, 0, stream>>>(
        H2, (const u16*)nullptr, W3t, (const u16*)nullptr, b3cat, Y3, n);
    agg_cat32<<<idiv(n, 16), 256, 0, stream>>>(Y3, rp, colx, dinv, out, n, E);
}

// Round 7
// 456.156 us; speedup vs baseline: 2.6060x; 1.1338x over previous
//
#include <hip/hip_runtime.h>
#include <hip/hip_fp16.h>
#include <math.h>

typedef unsigned short u16;
typedef unsigned int u32;
typedef unsigned char u8;
typedef __attribute__((ext_vector_type(8))) short bf16x8;
typedef __attribute__((ext_vector_type(4))) float f32x4;

static inline int idiv(int a, int b) { return (a + b - 1) / b; }

__device__ inline float b2f_lo(u32 w) { return __uint_as_float((w & 0xFFFFu) << 16); }
__device__ inline float b2f_hi(u32 w) { return __uint_as_float(w & 0xFFFF0000u); }
__device__ inline u32 f2b_rne(float f) {            // round-to-nearest-even bf16 bits
    u32 x = __float_as_uint(f);
    return (x + 0x7FFFu + ((x >> 16) & 1u)) >> 16;
}

// ---------------- fp8 e4m3 encode/decode (HW cvt if available) ----------------
#if defined(__has_builtin)
#if __has_builtin(__builtin_amdgcn_cvt_pk_f32_fp8) && __has_builtin(__builtin_amdgcn_cvt_pk_fp8_f32)
#define FP8_HW 1
#endif
#endif

__device__ inline float fp8_dec1_sw(u32 b) {
    u32 s = (b & 0x80u) << 24;
    u32 em = b & 0x7Fu;
    if (em >= 8u) {                     // normal
        u32 e = em >> 3, m = em & 7u;
        return __uint_as_float(s | ((e + 120u) << 23) | (m << 20));
    }
    float v = (float)(int)em * 0.001953125f;   // subnormal: m * 2^-9
    return (b & 0x80u) ? -v : v;
}
__device__ inline u32 fp8_enc1_sw(float f) {
    __half hh = __float2half(f * 0.00390625f);  // 2^-8 scale into f16 domain
    u16 hb = __half_as_ushort(hh);
    u32 mag = hb & 0x7FFFu;
    u32 rm = (mag + 0x3Fu + ((mag >> 7) & 1u)) >> 7;
    if (rm > 0x7Eu) rm = 0x7Eu;                 // clamp to max finite
    return ((hb >> 8) & 0x80u) | rm;
}

__device__ inline void fp8x4_dec(u32 w, float o[4]) {
#ifdef FP8_HW
    auto lo = __builtin_amdgcn_cvt_pk_f32_fp8((int)w, false);
    auto hi = __builtin_amdgcn_cvt_pk_f32_fp8((int)w, true);
    o[0] = lo[0]; o[1] = lo[1]; o[2] = hi[0]; o[3] = hi[1];
#else
    o[0] = fp8_dec1_sw(w & 0xFFu); o[1] = fp8_dec1_sw((w >> 8) & 0xFFu);
    o[2] = fp8_dec1_sw((w >> 16) & 0xFFu); o[3] = fp8_dec1_sw(w >> 24);
#endif
}
__device__ inline void fp8x2_dec(u32 w, float o[2]) {   // low 2 bytes
#ifdef FP8_HW
    auto lo = __builtin_amdgcn_cvt_pk_f32_fp8((int)w, false);
    o[0] = lo[0]; o[1] = lo[1];
#else
    o[0] = fp8_dec1_sw(w & 0xFFu); o[1] = fp8_dec1_sw((w >> 8) & 0xFFu);
#endif
}
__device__ inline u32 fp8_enc1(float v) {
#ifdef FP8_HW
    return (u32)__builtin_amdgcn_cvt_pk_fp8_f32(v, v, 0, false) & 0xFFu;
#else
    return fp8_enc1_sw(v);
#endif
}
__device__ inline u32 fp8x4_enc(float a, float b, float c, float d) {
#ifdef FP8_HW
    int p = __builtin_amdgcn_cvt_pk_fp8_f32(a, b, 0, false);
    p = __builtin_amdgcn_cvt_pk_fp8_f32(c, d, p, true);
    return (u32)p;
#else
    return fp8_enc1_sw(a) | (fp8_enc1_sw(b) << 8) | (fp8_enc1_sw(c) << 16) | (fp8_enc1_sw(d) << 24);
#endif
}

// async global->LDS, 16 B per lane (LDS dest wave-uniform base + lane*16)
__device__ __forceinline__ void g2lds16(const u16* gsrc, u16* ldsbase) {
    __builtin_amdgcn_global_load_lds(
        (const __attribute__((address_space(1))) u32*)gsrc,
        (__attribute__((address_space(3))) u32*)ldsbase, 16, 0, 0);
}

// ---------------- CSR build (verified round 5) ----------------

__global__ void hist_xcd(const int* __restrict__ dst, int E, int n, int* __restrict__ cnt) {
    const int part = blockIdx.x & 7;
    const int ch   = blockIdx.x >> 3;
    const int nch  = gridDim.x >> 3;
    const int lo = (int)((long long)n * part / 8);
    const int hi = (int)((long long)n * (part + 1) / 8);
    const int e0 = (int)((long long)E * ch / nch);
    const int e1 = (int)((long long)E * (ch + 1) / nch);
    for (int e = e0 + (int)threadIdx.x; e < e1; e += 256) {
        int d = dst[e];
        if (d >= lo && d < hi) atomicAdd(&cnt[d], 1);
    }
}

__global__ void fill_xcd(const int* __restrict__ src, const int* __restrict__ dst,
                         int E, int n, int* __restrict__ cur, int* __restrict__ col) {
    const int part = blockIdx.x & 7;
    const int ch   = blockIdx.x >> 3;
    const int nch  = gridDim.x >> 3;
    const int lo = (int)((long long)n * part / 8);
    const int hi = (int)((long long)n * (part + 1) / 8);
    const int e0 = (int)((long long)E * ch / nch);
    const int e1 = (int)((long long)E * (ch + 1) / nch);
    for (int e = e0 + (int)threadIdx.x; e < e1; e += 256) {
        int d = dst[e];
        int s = src[e];
        if (d >= lo && d < hi) {
            int p = atomicAdd(&cur[d], 1);
            if ((unsigned)s >= (unsigned)n) s = 0;
            col[p] = s;
        }
    }
}

__global__ void scan1_kernel(const int* __restrict__ cnt, int n,
                             int* __restrict__ rp, int* __restrict__ bsum) {
    __shared__ int s[256];
    int i = blockIdx.x * 256 + threadIdx.x;
    int v = (i < n) ? cnt[i] : 0;
    s[threadIdx.x] = v;
    __syncthreads();
    for (int off = 1; off < 256; off <<= 1) {
        int t = (threadIdx.x >= off) ? s[threadIdx.x - off] : 0;
        __syncthreads();
        s[threadIdx.x] += t;
        __syncthreads();
    }
    if (i < n) rp[i] = s[threadIdx.x] - v;
    if (threadIdx.x == 255) bsum[blockIdx.x] = s[255];
}

__global__ void scan2_kernel(int* __restrict__ bsum, int nb) {
    __shared__ int s[512];
    int v = ((int)threadIdx.x < nb) ? bsum[threadIdx.x] : 0;
    s[threadIdx.x] = v;
    __syncthreads();
    for (int off = 1; off < 512; off <<= 1) {
        int t = (threadIdx.x >= off) ? s[threadIdx.x - off] : 0;
        __syncthreads();
        s[threadIdx.x] += t;
        __syncthreads();
    }
    if ((int)threadIdx.x < nb) bsum[threadIdx.x] = s[threadIdx.x] - v;
}

__global__ void scan3_kernel(int* __restrict__ rp, int* __restrict__ cur,
                             float* __restrict__ dinv, const int* __restrict__ bsum,
                             int n, int E) {
    int i = blockIdx.x * 256 + threadIdx.x;
    if (i < n) {
        int c = cur[i];                    // still the count
        int v = rp[i] + bsum[blockIdx.x];
        rp[i]  = v;
        cur[i] = v;
        dinv[i] = 1.0f / (float)(c > 1 ? c : 1);
    }
    if (i == 0) rp[n] = E;
}

// ---------------- fused prep (verified round 4) ----------------
__global__ void prep_all(const float* __restrict__ W1l, const float* __restrict__ W1r,
                         const float* __restrict__ W2l, const float* __restrict__ W2r,
                         const float* __restrict__ W3l, const float* __restrict__ W3r,
                         const float* __restrict__ b2, const float* __restrict__ b3,
                         u16* __restrict__ W1lt, u16* __restrict__ W1rt,
                         u16* __restrict__ W2t, u16* __restrict__ W3t,
                         float* __restrict__ b2cat, float* __restrict__ b3cat) {
    int i = blockIdx.x * 256 + threadIdx.x;
    if (i < 32768) {                       // W1l^T: K=128, N=256
        int nn = i >> 7, k = i & 127;
        W1lt[i] = (u16)f2b_rne(W1l[k * 256 + nn]);
        return;
    }
    i -= 32768;
    if (i < 32768) {
        int nn = i >> 7, k = i & 127;
        W1rt[i] = (u16)f2b_rne(W1r[k * 256 + nn]);
        return;
    }
    i -= 32768;
    if (i < 49152) {                       // W2l^T: K=256, N=192
        int nn = i >> 8, k = i & 255;
        W2t[i] = (u16)f2b_rne(W2l[k * 192 + nn]);
        return;
    }
    i -= 49152;
    if (i < 49152) {
        int nn = i >> 8, k = i & 255;
        W2t[192 * 256 + i] = (u16)f2b_rne(W2r[k * 192 + nn]);
        return;
    }
    i -= 49152;
    if (i < 6144) {                        // W3l^T: K=192, N=32
        int nn = i / 192, k = i - nn * 192;
        W3t[i] = (u16)f2b_rne(W3l[k * 32 + nn]);
        return;
    }
    i -= 6144;
    if (i < 6144) {
        int nn = i / 192, k = i - nn * 192;
        W3t[32 * 192 + i] = (u16)f2b_rne(W3r[k * 32 + nn]);
        return;
    }
    i -= 6144;
    if (i < 384) { b2cat[i] = (i < 192) ? 0.f : b2[i - 192]; return; }
    i -= 384;
    if (i < 64)  { b3cat[i] = (i < 32) ? 0.f : b3[i - 32]; }
}

// xb = bf16(x), xq = fp8(x); 8 elems/thread
__global__ void cvt_x_kernel(const float* __restrict__ x, u16* __restrict__ xb,
                             u8* __restrict__ xq, int total8) {
    int i = blockIdx.x * 256 + threadIdx.x;
    if (i >= total8) return;
    const float4 a = *(const float4*)(x + (size_t)i * 8);
    const float4 b = *(const float4*)(x + (size_t)i * 8 + 4);
    uint4 o;
    o.x = f2b_rne(a.x) | (f2b_rne(a.y) << 16);
    o.y = f2b_rne(a.z) | (f2b_rne(a.w) << 16);
    o.z = f2b_rne(b.x) | (f2b_rne(b.y) << 16);
    o.w = f2b_rne(b.z) | (f2b_rne(b.w) << 16);
    *(uint4*)(xb + (size_t)i * 8) = o;
    uint2 q;
    q.x = fp8x4_enc(a.x, a.y, a.z, a.w);
    q.y = fp8x4_enc(b.x, b.y, b.z, b.w);
    *(uint2*)(xq + (size_t)i * 8) = q;
}

// ---------------- aggregation kernels (fp8 gather paths) ----------------

// AGG1[i] = mean_j fp8(x)[col[j]]  (128 fp8 = 128 B/row). 2 nodes/wave,
// 32 lanes x 1 dword (4 fp8), unroll 4. Output bf16.
__global__ void agg_mean128(const u8* __restrict__ Xq, const int* __restrict__ rp,
                            const int* __restrict__ col, const float* __restrict__ dinv,
                            u16* __restrict__ A, int n, int E) {
    const int widx = (blockIdx.x * blockDim.x + threadIdx.x) >> 6;
    const int lane = threadIdx.x & 63;
    const int half = lane >> 5, sl = lane & 31;
    const int node = widx * 2 + half;
    const bool valid = node < n;
    const int s   = valid ? rp[node] : 0;
    const int deg = valid ? rp[node + 1] - s : 0;
    int m = deg;
    m = max(m, __shfl_xor(m, 32));
    const u32* Xg = (const u32*)Xq;        // row = 32 dwords (128 fp8)
    float a[4] = {0, 0, 0, 0}, c[4] = {0, 0, 0, 0};
    for (int t = 0; t < m; t += 4) {
        bool p0 = t < deg, p1 = t + 1 < deg, p2 = t + 2 < deg, p3 = t + 3 < deg;
        int i0 = min(s + t,     E - 1), i1 = min(s + t + 1, E - 1);
        int i2 = min(s + t + 2, E - 1), i3 = min(s + t + 3, E - 1);
        int e0 = col[i0], e1 = col[i1], e2 = col[i2], e3 = col[i3];
        u32 w0 = Xg[(size_t)e0 * 32 + sl];
        u32 w1 = Xg[(size_t)e1 * 32 + sl];
        u32 w2 = Xg[(size_t)e2 * 32 + sl];
        u32 w3 = Xg[(size_t)e3 * 32 + sl];
        if (!p0) w0 = 0;
        if (!p1) w1 = 0;
        if (!p2) w2 = 0;
        if (!p3) w3 = 0;
        float d0[4], d1[4], d2[4], d3[4];
        fp8x4_dec(w0, d0); fp8x4_dec(w1, d1); fp8x4_dec(w2, d2); fp8x4_dec(w3, d3);
#pragma unroll
        for (int j = 0; j < 4; ++j) { a[j] += d0[j] + d2[j]; c[j] += d1[j] + d3[j]; }
    }
    if (valid) {
        const float inv = dinv[node];
        uint2 o;
        o.x = f2b_rne((a[0] + c[0]) * inv) | (f2b_rne((a[1] + c[1]) * inv) << 16);
        o.y = f2b_rne((a[2] + c[2]) * inv) | (f2b_rne((a[3] + c[3]) * inv) << 16);
        *((uint2*)A + (size_t)node * 32 + sl) = o;
    }
}

// H2[i] = relu(mean_j Y2q[col[j]] + Y2r[i]).
// Y2q: fp8, 192 B/row (cols 0-191). Y2r: bf16, 192 elems/row (cols 192-383).
// 2 nodes/wave, 32 lanes: dword @4sl (4 fp8) + ushort @128+2sl (2 fp8). Unroll 3.
__global__ void agg_cat192(const u8* __restrict__ Yq, const u16* __restrict__ Yr,
                           const int* __restrict__ rp, const int* __restrict__ col,
                           const float* __restrict__ dinv, u16* __restrict__ H,
                           int n, int E) {
    const int widx = (blockIdx.x * blockDim.x + threadIdx.x) >> 6;
    const int lane = threadIdx.x & 63;
    const int half = lane >> 5, sl = lane & 31;
    const int node = widx * 2 + half;
    const bool valid = node < n;
    const int s   = valid ? rp[node] : 0;
    const int deg = valid ? rp[node + 1] - s : 0;
    int m = deg;
    m = max(m, __shfl_xor(m, 32));
    const int offd = 4 * sl, offs = 128 + 2 * sl;
    float a[6] = {0, 0, 0, 0, 0, 0};
    float b[6] = {0, 0, 0, 0, 0, 0};
    float c[6] = {0, 0, 0, 0, 0, 0};
    for (int t = 0; t < m; t += 3) {
        bool p0 = t < deg, p1 = t + 1 < deg, p2 = t + 2 < deg;
        int i0 = min(s + t, E - 1), i1 = min(s + t + 1, E - 1), i2 = min(s + t + 2, E - 1);
        int e0 = col[i0], e1 = col[i1], e2 = col[i2];
        const u8* r0 = Yq + (size_t)e0 * 192;
        const u8* r1 = Yq + (size_t)e1 * 192;
        const u8* r2 = Yq + (size_t)e2 * 192;
        u32 w0 = *(const u32*)(r0 + offd);
        u32 w1 = *(const u32*)(r1 + offd);
        u32 w2 = *(const u32*)(r2 + offd);
        u32 s0 = *(const u16*)(r0 + offs);
        u32 s1 = *(const u16*)(r1 + offs);
        u32 s2 = *(const u16*)(r2 + offs);
        if (!p0) { w0 = 0; s0 = 0; }
        if (!p1) { w1 = 0; s1 = 0; }
        if (!p2) { w2 = 0; s2 = 0; }
        float d[4], e2f[2];
        fp8x4_dec(w0, d); fp8x2_dec(s0, e2f);
        a[0] += d[0]; a[1] += d[1]; a[2] += d[2]; a[3] += d[3];
        a[4] += e2f[0]; a[5] += e2f[1];
        fp8x4_dec(w1, d); fp8x2_dec(s1, e2f);
        b[0] += d[0]; b[1] += d[1]; b[2] += d[2]; b[3] += d[3];
        b[4] += e2f[0]; b[5] += e2f[1];
        fp8x4_dec(w2, d); fp8x2_dec(s2, e2f);
        c[0] += d[0]; c[1] += d[1]; c[2] += d[2]; c[3] += d[3];
        c[4] += e2f[0]; c[5] += e2f[1];
    }
    if (valid) {
        const float inv = dinv[node];
        // self: Y2r row (bf16, 384 B); lane's cols: 2sl..2sl+3 (uint2) + 128+... pattern:
        // gather lane covers cols {4sl..4sl+3, 128+2sl, 129+2sl}; match with self reads:
        const char* rs = (const char*)Yr + (size_t)node * 384;
        uint2 ru = *(const uint2*)(rs + 8 * sl);        // cols 4sl..4sl+3
        u32   rd = *(const u32*)(rs + 256 + 4 * sl);    // cols 128+2sl..+1
        float o0 = fmaxf((a[0] + b[0] + c[0]) * inv + b2f_lo(ru.x), 0.f);
        float o1 = fmaxf((a[1] + b[1] + c[1]) * inv + b2f_hi(ru.x), 0.f);
        float o2 = fmaxf((a[2] + b[2] + c[2]) * inv + b2f_lo(ru.y), 0.f);
        float o3 = fmaxf((a[3] + b[3] + c[3]) * inv + b2f_hi(ru.y), 0.f);
        float o4 = fmaxf((a[4] + b[4] + c[4]) * inv + b2f_lo(rd), 0.f);
        float o5 = fmaxf((a[5] + b[5] + c[5]) * inv + b2f_hi(rd), 0.f);
        char* hb = (char*)H + (size_t)node * 384;
        uint2 ou; ou.x = f2b_rne(o0) | (f2b_rne(o1) << 16);
        ou.y = f2b_rne(o2) | (f2b_rne(o3) << 16);
        *(uint2*)(hb + 8 * sl) = ou;
        *(u32*)(hb + 256 + 4 * sl) = f2b_rne(o4) | (f2b_rne(o5) << 16);
    }
}

// out[i] = sigmoid(mean_j Y[col[j]][0:32] + Y[i][32:64]). 4 nodes/wave, unroll 4. (verified r4)
__global__ void agg_cat32(const u16* __restrict__ Y, const int* __restrict__ rp,
                          const int* __restrict__ col, const float* __restrict__ dinv,
                          float* __restrict__ out, int n, int E) {
    const int widx = (blockIdx.x * blockDim.x + threadIdx.x) >> 6;
    const int lane = threadIdx.x & 63;
    const int grp = lane >> 4, sl = lane & 15;
    const int node = widx * 4 + grp;
    const bool valid = node < n;
    const int s   = valid ? rp[node] : 0;
    const int deg = valid ? rp[node + 1] - s : 0;
    int m = deg;
    m = max(m, __shfl_xor(m, 16));
    m = max(m, __shfl_xor(m, 32));
    const u32* Yw = (const u32*)Y;         // row = 32 dwords (64 bf16)
    float a0 = 0, a1 = 0, b0 = 0, b1 = 0;
    for (int t = 0; t < m; t += 4) {
        bool p0 = t < deg, p1 = t + 1 < deg, p2 = t + 2 < deg, p3 = t + 3 < deg;
        int i0 = min(s + t,     E - 1), i1 = min(s + t + 1, E - 1);
        int i2 = min(s + t + 2, E - 1), i3 = min(s + t + 3, E - 1);
        int e0 = col[i0], e1 = col[i1], e2 = col[i2], e3 = col[i3];
        u32 w0 = Yw[(size_t)e0 * 32 + sl];
        u32 w1 = Yw[(size_t)e1 * 32 + sl];
        u32 w2 = Yw[(size_t)e2 * 32 + sl];
        u32 w3 = Yw[(size_t)e3 * 32 + sl];
        if (!p0) w0 = 0;
        if (!p1) w1 = 0;
        if (!p2) w2 = 0;
        if (!p3) w3 = 0;
        a0 += b2f_lo(w0); a1 += b2f_hi(w0);
        b0 += b2f_lo(w1); b1 += b2f_hi(w1);
        a0 += b2f_lo(w2); a1 += b2f_hi(w2);
        b0 += b2f_lo(w3); b1 += b2f_hi(w3);
    }
    if (valid) {
        const float inv = dinv[node];
        u32 rv = Yw[(size_t)node * 32 + 16 + sl];
        float o0 = 1.f / (1.f + __expf(-((a0 + b0) * inv + b2f_lo(rv))));
        float o1 = 1.f / (1.f + __expf(-((a1 + b1) * inv + b2f_hi(rv))));
        *(float2*)(out + (size_t)node * 32 + sl * 2) = make_float2(o0, o1);
    }
}

// ---------------- MFMA GEMM (global_load_lds staging, verified r6) ----------------
// out = act(A1@B1t^T [+ A2@B2t^T] + bias).
// SPLITQ (layer 2): cols<192 -> fp8 byte to outq (stride 192); cols>=192 ->
// bf16 to out (stride 192, col-192). Else: bf16 to out (stride NDIM).
template <int KDIM, int NDIM, int BN, int ACT, bool DUAL, bool SPLITQ>
__global__ __launch_bounds__(256)
void gemm_mfma(const u16* __restrict__ A1, const u16* __restrict__ A2,
               const u16* __restrict__ B1t, const u16* __restrict__ B2t,
               const float* __restrict__ bias, u16* __restrict__ out,
               u8* __restrict__ outq, int M) {
    constexpr int BM = 128;
    constexpr int WR = (BN == 128) ? 2 : 4;
    constexpr int MF = BM / WR / 16;
    constexpr int NF = 4;
    __shared__ u16 As[BM * 64];
    __shared__ u16 Bs[BN * 64];

    const int row0 = blockIdx.x * BM;
    const int bn0  = blockIdx.y * BN;
    const int t    = threadIdx.x;
    const int wid  = t >> 6, ln = t & 63;
    const int lr   = ln >> 3;          // row-within-8 (== swizzle key)
    const int lc   = ln & 7;           // chunk
    const int ln15 = ln & 15, lg = ln >> 4;
    const int wr = (BN == 128) ? (wid >> 1) : wid;
    const int wc = (BN == 128) ? (wid & 1) : 0;
    const int wrow0 = wr * (BM / WR);
    const int wcol0 = wc * 64;
    const int swch  = (lc ^ lr) * 8;   // pre-swizzled source chunk offset (elems)

    f32x4 acc[MF][NF];
#pragma unroll
    for (int m = 0; m < MF; ++m)
#pragma unroll
        for (int nn = 0; nn < NF; ++nn) acc[m][nn] = (f32x4){0.f, 0.f, 0.f, 0.f};

#pragma unroll
    for (int s = 0; s < (DUAL ? 2 : 1); ++s) {
        const u16* A  = (DUAL && s) ? A2 : A1;
        const u16* Bt = (DUAL && s) ? B2t : B1t;
        for (int kt = 0; kt < KDIM / 64; ++kt) {
            const int k0 = kt * 64;
#pragma unroll
            for (int it = 0; it < 4; ++it) {
                int rloc = it * 32 + 8 * wid + lr;
                int grow = row0 + rloc; if (grow >= M) grow = M - 1;
                g2lds16(A + (size_t)grow * KDIM + k0 + swch,
                        As + (it * 32 + 8 * wid) * 64);
            }
#pragma unroll
            for (int it = 0; it < BN / 32; ++it) {
                int rloc = it * 32 + 8 * wid + lr;
                g2lds16(Bt + (size_t)(bn0 + rloc) * KDIM + k0 + swch,
                        Bs + (it * 32 + 8 * wid) * 64);
            }
            __syncthreads();   // drains vmcnt for global_load_lds
#pragma unroll
            for (int ks = 0; ks < 2; ++ks) {
                bf16x8 af[MF], bfr[NF];
#pragma unroll
                for (int m = 0; m < MF; ++m) {
                    int r  = wrow0 + m * 16 + ln15;
                    int ch = (ks * 4 + lg) ^ (r & 7);
                    af[m] = *(const bf16x8*)(As + r * 64 + ch * 8);
                }
#pragma unroll
                for (int nn = 0; nn < NF; ++nn) {
                    int r  = wcol0 + nn * 16 + ln15;
                    int ch = (ks * 4 + lg) ^ (r & 7);
                    bfr[nn] = *(const bf16x8*)(Bs + r * 64 + ch * 8);
                }
#pragma unroll
                for (int m = 0; m < MF; ++m)
#pragma unroll
                    for (int nn = 0; nn < NF; ++nn)
                        acc[m][nn] = __builtin_amdgcn_mfma_f32_16x16x32_bf16(
                            af[m], bfr[nn], acc[m][nn], 0, 0, 0);
            }
            __syncthreads();
        }
    }

    // epilogue: C/D layout col = lane&15, row = (lane>>4)*4 + reg
#pragma unroll
    for (int nn = 0; nn < NF; ++nn) {
        const int col = bn0 + wcol0 + nn * 16 + ln15;
        const float bv = bias[col];
#pragma unroll
        for (int m = 0; m < MF; ++m) {
#pragma unroll
            for (int r = 0; r < 4; ++r) {
                int row = row0 + wrow0 + m * 16 + lg * 4 + r;
                if (row < M) {
                    float v = acc[m][nn][r] + bv;
                    if (ACT == 0) v = tanhf(v);
                    if (SPLITQ) {
                        if (col < 192) outq[(size_t)row * 192 + col] = (u8)fp8_enc1(v);
                        else out[(size_t)row * 192 + (col - 192)] = (u16)f2b_rne(v);
                    } else {
                        out[(size_t)row * NDIM + col] = (u16)f2b_rne(v);
                    }
                }
            }
        }
    }
}

// ---------------- launch ----------------

extern "C" void kernel_launch(void* const* d_in, const int* in_sizes, int n_in,
                              void* d_out, int out_size, void* d_ws, size_t ws_size,
                              hipStream_t stream) {
    const float* x   = (const float*)d_in[0];
    const int*   ei  = (const int*)  d_in[1];
    const float* W1l = (const float*)d_in[2];
    const float* W1r = (const float*)d_in[3];
    const float* b1  = (const float*)d_in[4];
    const float* W2l = (const float*)d_in[5];
    const float* W2r = (const float*)d_in[6];
    const float* b2  = (const float*)d_in[7];
    const float* W3l = (const float*)d_in[8];
    const float* W3r = (const float*)d_in[9];
    const float* b3  = (const float*)d_in[10];
    float* out = (float*)d_out;

    const int n = in_sizes[0] / 128;   // 100000
    const int E = in_sizes[1] / 2;     // 1600000
    const int* esrc = ei;
    const int* edst = ei + E;

    char* ws = (char*)d_ws;
    size_t off = 0;
    auto alloc = [&](size_t bytes) -> void* {
        void* p = ws + off;
        off += (bytes + 255) & ~(size_t)255;
        return p;
    };
    int*   rp    = (int*)  alloc((size_t)(n + 1) * 4);
    int*   cur   = (int*)  alloc((size_t)n * 4);
    int*   colx  = (int*)  alloc((size_t)E * 4);
    float* dinv  = (float*)alloc((size_t)n * 4);
    int*   bsum  = (int*)  alloc(512 * 4);
    u16*   W1lt  = (u16*)  alloc(256 * 128 * 2);
    u16*   W1rt  = (u16*)  alloc(256 * 128 * 2);
    u16*   W2t   = (u16*)  alloc(384 * 256 * 2);
    u16*   W3t   = (u16*)  alloc(64 * 192 * 2);
    float* b2cat = (float*)alloc(384 * 4);
    float* b3cat = (float*)alloc(64 * 4);
    u16*   Sa    = (u16*)  alloc((size_t)n * 384 * 2);  // overlay pool A (76.8 MB)
    u16*   Sb    = (u16*)  alloc((size_t)n * 256 * 2);  // overlay pool B (51.2 MB)

    if (off > ws_size) return;   // insufficient workspace: fail cleanly (no fault)

    // pool A overlays:
    u16* xb   = Sa;                                   // n*128 bf16 (25.6 MB)
    u16* AGG1 = Sa + (size_t)n * 128;                 // n*128 bf16 (25.6 MB)
    u8*  xq   = (u8*)(Sa + (size_t)n * 256);          // n*128 fp8  (12.8 MB)
    u16* Y2r  = Sa;                                   // n*192 bf16 (38.4 MB) [after L1]
    u8*  Y2q  = (u8*)(Sa + (size_t)n * 192);          // n*192 fp8  (19.2 MB)
    u16* Y3   = Sa;                                   // n*64 bf16  (12.8 MB) [after L2 agg]
    // pool B overlays:
    u16* H1   = Sb;                                   // n*256 bf16
    u16* H2   = Sb;                                   // n*192 bf16 [after L2 GEMM]

    const int NB = idiv(n, 256);
    const int GX = idiv(n, 128);
    const int SCAT_GRID = 8 * 192;   // 8 dst-ranges x 192 chunks

    // CSR
    hipMemsetAsync(cur, 0, (size_t)n * 4, stream);
    hist_xcd<<<SCAT_GRID, 256, 0, stream>>>(edst, E, n, cur);
    scan1_kernel<<<NB, 256, 0, stream>>>(cur, n, rp, bsum);
    scan2_kernel<<<1, 512, 0, stream>>>(bsum, NB);
    scan3_kernel<<<NB, 256, 0, stream>>>(rp, cur, dinv, bsum, n, E);
    fill_xcd<<<SCAT_GRID, 256, 0, stream>>>(esrc, edst, E, n, cur, colx);

    // prep: weights (bf16/transposed/concatenated) + bias cats + xb/xq
    prep_all<<<idiv(176576, 256), 256, 0, stream>>>(
        W1l, W1r, W2l, W2r, W3l, W3r, b2, b3, W1lt, W1rt, W2t, W3t, b2cat, b3cat);
    cvt_x_kernel<<<idiv(n * 16, 256), 256, 0, stream>>>(x, xb, xq, n * 16);

    // layer 1 (aggregate-first): H1 = tanh(AGG1@W1l + xb@W1r + b1); mean path fp8
    agg_mean128<<<idiv(n, 8), 256, 0, stream>>>(xq, rp, colx, dinv, AGG1, n, E);
    gemm_mfma<128, 256, 128, 0, true, false><<<dim3(GX, 2), 256, 0, stream>>>(
        AGG1, xb, W1lt, W1rt, b1, H1, (u8*)nullptr, n);

    // layer 2 (transform-first): Y2l(fp8)+Y2r(bf16) = H1@[W2l|W2r] + [0|b2];
    // H2 = relu(mean(Y2q) + Y2r)
    gemm_mfma<256, 384, 128, -1, false, true><<<dim3(GX, 3), 256, 0, stream>>>(
        H1, (const u16*)nullptr, W2t, (const u16*)nullptr, b2cat, Y2r, Y2q, n);
    agg_cat192<<<idiv(n, 8), 256, 0, stream>>>(Y2q, Y2r, rp, colx, dinv, H2, n, E);

    // layer 3 (transform-first): Y3 = H2@[W3l|W3r] + [0|b3]; out = sigmoid(agg(Y3l)+Y3r)
    gemm_mfma<192, 64, 64, -1, false, false><<<dim3(GX, 1), 256, 0, stream>>>(
        H2, (const u16*)nullptr, W3t, (const u16*)nullptr, b3cat, Y3, (u8*)nullptr, n);
    agg_cat32<<<idiv(n, 16), 256, 0, stream>>>(Y3, rp, colx, dinv, out, n, E);
}